// Round 1
// baseline (607.517 us; speedup 1.0000x reference)
//
#include <hip/hip_runtime.h>
#include <hip/hip_bf16.h>
#include <math.h>

// Problem constants (from reference): N=20000 nodes, E=320000 edges,
// D_IN=256, HID=128, HEADS=2 -> all layer GEMMs are [N,256]@[256,256].
#define NCH 256            // channels per node vector (H*C)
#define LEAKY 0.2f

// ---------------------------------------------------------------------------
// CSR build: counts -> scan -> scatter
// ---------------------------------------------------------------------------
__global__ void count_kernel(const int* __restrict__ ei, int E, int n,
                             int* __restrict__ counts) {
    int tid = blockIdx.x * 256 + threadIdx.x;
    int tot = E + n;
    if (tid >= tot) return;
    int dst = (tid < E) ? ei[E + tid] : (tid - E);   // self-loop for tid>=E
    atomicAdd(&counts[dst], 1);
}

__global__ void scan_kernel(const int* __restrict__ counts,
                            int* __restrict__ offsets,
                            int* __restrict__ cursor, int n) {
    __shared__ int wsum[16];
    int tid  = threadIdx.x;          // 1024 threads = 16 waves
    int lane = tid & 63, w = tid >> 6;
    int carry = 0;
    for (int base = 0; base < n; base += 1024) {
        int idx = base + tid;
        int v = (idx < n) ? counts[idx] : 0;
        int incl = v;
        #pragma unroll
        for (int off = 1; off < 64; off <<= 1) {
            int t2 = __shfl_up(incl, off, 64);
            if (lane >= off) incl += t2;
        }
        if (lane == 63) wsum[w] = incl;
        __syncthreads();
        if (w == 0 && lane < 16) {
            int s = wsum[lane];
            #pragma unroll
            for (int off = 1; off < 16; off <<= 1) {
                int t2 = __shfl_up(s, off, 64);
                if (lane >= off) s += t2;
            }
            wsum[lane] = s;          // inclusive scan of wave sums
        }
        __syncthreads();
        int wpre = (w == 0) ? 0 : wsum[w - 1];
        int excl = carry + wpre + incl - v;
        if (idx < n) { offsets[idx] = excl; cursor[idx] = excl; }
        carry += wsum[15];
        __syncthreads();             // protect wsum before next tile
    }
    if (tid == 0) offsets[n] = carry;
}

__global__ void scatter_kernel(const int* __restrict__ ei, int E, int n,
                               int* __restrict__ cursor,
                               int* __restrict__ csr_src) {
    int tid = blockIdx.x * 256 + threadIdx.x;
    int tot = E + n;
    if (tid >= tot) return;
    int src, dst;
    if (tid < E) { src = ei[tid]; dst = ei[E + tid]; }
    else         { src = dst = tid - E; }
    int pos = atomicAdd(&cursor[dst], 1);
    csr_src[pos] = src;
}

// ---------------------------------------------------------------------------
// Dual GEMM: xl = A@Wl, xr = A@Wr.  A:[M,256], Wl/Wr:[256,256].
// Block tile 128 rows x 128 cols (grid.y: 0,1 -> Wl cols 0/128; 2,3 -> Wr).
// 8x8 micro-tile split as 2x2 blocks of 4x4 at offsets {0,64} so all LDS
// reads are float4 with conflict-free / 2-way banks.
// ---------------------------------------------------------------------------
#define TK 16
__global__ __launch_bounds__(256) void dual_gemm(
        const float* __restrict__ A,
        const float* __restrict__ Wl, const float* __restrict__ Wr,
        float* __restrict__ xl, float* __restrict__ xr, int M) {
    __shared__ float Ast[TK][128];   // A transposed: Ast[k][row]
    __shared__ float Bs[TK][128];
    int cb = blockIdx.y;             // 0..3
    const float* B = (cb < 2) ? Wl : Wr;
    float* Out     = (cb < 2) ? xl : xr;
    int col0 = (cb & 1) * 128;
    int row0 = blockIdx.x * 128;
    int t  = threadIdx.x;
    int tr = t >> 4, tc = t & 15;    // 16x16 thread grid
    float acc[8][8];
    #pragma unroll
    for (int i = 0; i < 8; ++i)
        #pragma unroll
        for (int j = 0; j < 8; ++j) acc[i][j] = 0.f;

    for (int k0 = 0; k0 < 256; k0 += TK) {
        #pragma unroll
        for (int h = 0; h < 2; ++h) {
            int f = h * 256 + t;             // float4 id, 512 total
            // A tile 128x16 -> transposed store
            int arow = f >> 2;               // 4 float4 per row
            int kk   = (f & 3) * 4;
            int gr   = row0 + arow;
            float4 a4 = (gr < M) ? *(const float4*)&A[(size_t)gr * NCH + k0 + kk]
                                 : make_float4(0.f, 0.f, 0.f, 0.f);
            Ast[kk + 0][arow] = a4.x;
            Ast[kk + 1][arow] = a4.y;
            Ast[kk + 2][arow] = a4.z;
            Ast[kk + 3][arow] = a4.w;
            // B tile 16x128
            int brow = f >> 5;               // 32 float4 per row
            int bc4  = (f & 31) * 4;
            float4 b4 = *(const float4*)&B[(size_t)(k0 + brow) * NCH + col0 + bc4];
            *(float4*)&Bs[brow][bc4] = b4;
        }
        __syncthreads();
        #pragma unroll
        for (int k = 0; k < TK; ++k) {
            float4 a0 = *(const float4*)&Ast[k][tr * 4];
            float4 a1 = *(const float4*)&Ast[k][64 + tr * 4];
            float4 b0 = *(const float4*)&Bs[k][tc * 4];
            float4 b1 = *(const float4*)&Bs[k][64 + tc * 4];
            float av[8] = {a0.x, a0.y, a0.z, a0.w, a1.x, a1.y, a1.z, a1.w};
            float bv[8] = {b0.x, b0.y, b0.z, b0.w, b1.x, b1.y, b1.z, b1.w};
            #pragma unroll
            for (int i = 0; i < 8; ++i)
                #pragma unroll
                for (int j = 0; j < 8; ++j)
                    acc[i][j] = fmaf(av[i], bv[j], acc[i][j]);
        }
        __syncthreads();
    }
    #pragma unroll
    for (int i = 0; i < 8; ++i) {
        int r = row0 + ((i < 4) ? (tr * 4 + i) : (64 + tr * 4 + (i - 4)));
        if (r >= M) continue;
        #pragma unroll
        for (int jb = 0; jb < 2; ++jb) {
            float4 v;
            v.x = acc[i][jb * 4 + 0];
            v.y = acc[i][jb * 4 + 1];
            v.z = acc[i][jb * 4 + 2];
            v.w = acc[i][jb * 4 + 3];
            int c = col0 + jb * 64 + tc * 4;
            *(float4*)&Out[(size_t)r * NCH + c] = v;
        }
    }
}

// ---------------------------------------------------------------------------
// GAT per-node kernel: wave per node. lane holds channels [4*lane, 4*lane+4).
// Heads: lanes 0..31 = head0 (c 0..127), 32..63 = head1.
// Pass1: e = att . leaky_relu(xl[src]+xr[dst]) per edge, ex=exp(e),
//        denominator accumulated in-register (max-subtraction skipped; e is
//        O(1) with these scales so exp is fp32-safe and alpha is identical).
// Pass2: out = sum alpha * xl[src]; + bias, relu.
// ---------------------------------------------------------------------------
__global__ __launch_bounds__(256) void gat_agg(
        const float* __restrict__ xl, const float* __restrict__ xr,
        const float* __restrict__ att, const float* __restrict__ bias,
        const int* __restrict__ offsets, const int* __restrict__ csr_src,
        float* __restrict__ csr_ex, float* __restrict__ hout, int nNodes) {
    int wid  = threadIdx.x >> 6;
    int lane = threadIdx.x & 63;
    int node = blockIdx.x * 4 + wid;
    if (node >= nNodes) return;
    int c0 = lane * 4;
    float4 att4 = *(const float4*)&att[c0];
    float4 xr4  = *(const float4*)&xr[(size_t)node * NCH + c0];
    int begin = offsets[node], end = offsets[node + 1];

    float denom = 0.f;
    for (int s = begin; s < end; ++s) {
        int src = csr_src[s];
        float4 xl4 = *(const float4*)&xl[(size_t)src * NCH + c0];
        float mx = xl4.x + xr4.x; mx = mx > 0.f ? mx : LEAKY * mx;
        float my = xl4.y + xr4.y; my = my > 0.f ? my : LEAKY * my;
        float mz = xl4.z + xr4.z; mz = mz > 0.f ? mz : LEAKY * mz;
        float mw = xl4.w + xr4.w; mw = mw > 0.f ? mw : LEAKY * mw;
        float p = mx * att4.x + my * att4.y + mz * att4.z + mw * att4.w;
        #pragma unroll
        for (int off = 16; off > 0; off >>= 1) p += __shfl_xor(p, off, 32);
        float ex = expf(p);
        denom += ex;
        if (lane == 0)       csr_ex[2 * s]     = ex;
        else if (lane == 32) csr_ex[2 * s + 1] = ex;
    }
    float rd = 1.0f / denom;
    int head = lane >> 5;

    float4 acc = make_float4(0.f, 0.f, 0.f, 0.f);
    for (int s = begin; s < end; ++s) {
        int src = csr_src[s];
        float alpha = csr_ex[2 * s + head] * rd;
        float4 xl4 = *(const float4*)&xl[(size_t)src * NCH + c0];
        acc.x = fmaf(alpha, xl4.x, acc.x);
        acc.y = fmaf(alpha, xl4.y, acc.y);
        acc.z = fmaf(alpha, xl4.z, acc.z);
        acc.w = fmaf(alpha, xl4.w, acc.w);
    }
    float4 b4 = *(const float4*)&bias[c0];
    float4 o;
    o.x = acc.x + b4.x; o.x = o.x > 0.f ? o.x : 0.f;
    o.y = acc.y + b4.y; o.y = o.y > 0.f ? o.y : 0.f;
    o.z = acc.z + b4.z; o.z = o.z > 0.f ? o.z : 0.f;
    o.w = acc.w + b4.w; o.w = o.w > 0.f ? o.w : 0.f;
    *(float4*)&hout[(size_t)node * NCH + c0] = o;
}

// ---------------------------------------------------------------------------
// Final projection: out = h @ Wout[256,4] + bout. Wave per node.
// ---------------------------------------------------------------------------
__global__ __launch_bounds__(256) void out_gemm(
        const float* __restrict__ h, const float* __restrict__ Wout,
        const float* __restrict__ bout, float* __restrict__ out, int nNodes) {
    int wid  = threadIdx.x >> 6;
    int lane = threadIdx.x & 63;
    int node = blockIdx.x * 4 + wid;
    if (node >= nNodes) return;
    int c0 = lane * 4;
    float4 h4 = *(const float4*)&h[(size_t)node * NCH + c0];
    float hv[4] = {h4.x, h4.y, h4.z, h4.w};
    float p0 = 0.f, p1 = 0.f, p2 = 0.f, p3 = 0.f;
    #pragma unroll
    for (int j = 0; j < 4; ++j) {
        float4 w4 = *(const float4*)&Wout[(size_t)(c0 + j) * 4];
        p0 = fmaf(hv[j], w4.x, p0);
        p1 = fmaf(hv[j], w4.y, p1);
        p2 = fmaf(hv[j], w4.z, p2);
        p3 = fmaf(hv[j], w4.w, p3);
    }
    #pragma unroll
    for (int off = 32; off > 0; off >>= 1) {
        p0 += __shfl_xor(p0, off, 64);
        p1 += __shfl_xor(p1, off, 64);
        p2 += __shfl_xor(p2, off, 64);
        p3 += __shfl_xor(p3, off, 64);
    }
    if (lane == 0) {
        out[(size_t)node * 4 + 0] = p0 + bout[0];
        out[(size_t)node * 4 + 1] = p1 + bout[1];
        out[(size_t)node * 4 + 2] = p2 + bout[2];
        out[(size_t)node * 4 + 3] = p3 + bout[3];
    }
}

// ---------------------------------------------------------------------------
extern "C" void kernel_launch(void* const* d_in, const int* in_sizes, int n_in,
                              void* d_out, int out_size, void* d_ws, size_t ws_size,
                              hipStream_t stream) {
    const float* x  = (const float*)d_in[0];
    const int*   ei = (const int*)d_in[1];
    const float* Wl[3]  = {(const float*)d_in[2], (const float*)d_in[6],  (const float*)d_in[10]};
    const float* Wr[3]  = {(const float*)d_in[3], (const float*)d_in[7],  (const float*)d_in[11]};
    const float* att[3] = {(const float*)d_in[4], (const float*)d_in[8],  (const float*)d_in[12]};
    const float* bb[3]  = {(const float*)d_in[5], (const float*)d_in[9],  (const float*)d_in[13]};
    const float* Wout = (const float*)d_in[14];
    const float* bout = (const float*)d_in[15];

    int Nn   = in_sizes[0] / NCH;       // 20000
    int E    = in_sizes[1] / 2;         // 320000
    int Etot = E + Nn;                  // + self loops

    // workspace layout (all fp32 arrays first, 16B aligned)
    size_t NEf = (size_t)Nn * NCH;
    float* xl     = (float*)d_ws;
    float* xr     = xl + NEf;
    float* hA     = xr + NEf;
    float* hB     = hA + NEf;
    float* csr_ex = hB + NEf;                    // 2*Etot floats
    int*   counts  = (int*)(csr_ex + 2 * (size_t)Etot);
    int*   offsets = counts + Nn;                // Nn+1
    int*   cursor  = offsets + (Nn + 1);
    int*   csr_src = cursor + Nn;                // Etot

    // CSR build (by dst)
    hipMemsetAsync(counts, 0, (size_t)Nn * sizeof(int), stream);
    int ethreads = (Etot + 255) / 256;
    count_kernel<<<ethreads, 256, 0, stream>>>(ei, E, Nn, counts);
    scan_kernel<<<1, 1024, 0, stream>>>(counts, offsets, cursor, Nn);
    scatter_kernel<<<ethreads, 256, 0, stream>>>(ei, E, Nn, cursor, csr_src);

    dim3 ggrid((Nn + 127) / 128, 4);
    int  ngrid = (Nn + 3) / 4;

    const float* in = x;
    float* houts[3] = {hA, hB, hA};
    for (int l = 0; l < 3; ++l) {
        dual_gemm<<<ggrid, 256, 0, stream>>>(in, Wl[l], Wr[l], xl, xr, Nn);
        gat_agg<<<ngrid, 256, 0, stream>>>(xl, xr, att[l], bb[l],
                                           offsets, csr_src, csr_ex, houts[l], Nn);
        in = houts[l];
    }
    out_gemm<<<ngrid, 256, 0, stream>>>(in, Wout, bout, (float*)d_out, Nn);
}

// Round 2
// 438.703 us; speedup vs baseline: 1.3848x; 1.3848x over previous
//
#include <hip/hip_runtime.h>
#include <hip/hip_bf16.h>
#include <math.h>

// Problem constants (from reference): N=20000 nodes, E=320000 edges,
// D_IN=256, HID=128, HEADS=2 -> all layer GEMMs are [N,256]@[256,256].
#define NCH 256            // channels per node vector (H*C)
#define LEAKY 0.2f

// ---------------------------------------------------------------------------
// CSR build: counts -> scan -> scatter
// ---------------------------------------------------------------------------
__global__ void count_kernel(const int* __restrict__ ei, int E, int n,
                             int* __restrict__ counts) {
    int tid = blockIdx.x * 256 + threadIdx.x;
    int tot = E + n;
    if (tid >= tot) return;
    int dst = (tid < E) ? ei[E + tid] : (tid - E);   // self-loop for tid>=E
    atomicAdd(&counts[dst], 1);
}

__global__ void scan_kernel(const int* __restrict__ counts,
                            int* __restrict__ offsets,
                            int* __restrict__ cursor, int n) {
    __shared__ int wsum[16];
    int tid  = threadIdx.x;          // 1024 threads = 16 waves
    int lane = tid & 63, w = tid >> 6;
    int carry = 0;
    for (int base = 0; base < n; base += 1024) {
        int idx = base + tid;
        int v = (idx < n) ? counts[idx] : 0;
        int incl = v;
        #pragma unroll
        for (int off = 1; off < 64; off <<= 1) {
            int t2 = __shfl_up(incl, off, 64);
            if (lane >= off) incl += t2;
        }
        if (lane == 63) wsum[w] = incl;
        __syncthreads();
        if (w == 0 && lane < 16) {
            int s = wsum[lane];
            #pragma unroll
            for (int off = 1; off < 16; off <<= 1) {
                int t2 = __shfl_up(s, off, 64);
                if (lane >= off) s += t2;
            }
            wsum[lane] = s;          // inclusive scan of wave sums
        }
        __syncthreads();
        int wpre = (w == 0) ? 0 : wsum[w - 1];
        int excl = carry + wpre + incl - v;
        if (idx < n) { offsets[idx] = excl; cursor[idx] = excl; }
        carry += wsum[15];
        __syncthreads();             // protect wsum before next tile
    }
    if (tid == 0) offsets[n] = carry;
}

__global__ void scatter_kernel(const int* __restrict__ ei, int E, int n,
                               int* __restrict__ cursor,
                               int* __restrict__ csr_src) {
    int tid = blockIdx.x * 256 + threadIdx.x;
    int tot = E + n;
    if (tid >= tot) return;
    int src, dst;
    if (tid < E) { src = ei[tid]; dst = ei[E + tid]; }
    else         { src = dst = tid - E; }
    int pos = atomicAdd(&cursor[dst], 1);
    csr_src[pos] = src;
}

// ---------------------------------------------------------------------------
// Dual GEMM: xl = A@Wl, xr = A@Wr.  A:[M,256], Wl/Wr:[256,256].
// Block tile 128 rows x 128 cols (grid.y: 0,1 -> Wl cols 0/128; 2,3 -> Wr).
// 8x8 micro-tile split as 2x2 blocks of 4x4 at offsets {0,64} so all LDS
// reads are float4 with conflict-free / 2-way banks.
// ---------------------------------------------------------------------------
#define TK 16
__global__ __launch_bounds__(256) void dual_gemm(
        const float* __restrict__ A,
        const float* __restrict__ Wl, const float* __restrict__ Wr,
        float* __restrict__ xl, float* __restrict__ xr, int M) {
    __shared__ float Ast[TK][128];   // A transposed: Ast[k][row]
    __shared__ float Bs[TK][128];
    int cb = blockIdx.y;             // 0..3
    const float* B = (cb < 2) ? Wl : Wr;
    float* Out     = (cb < 2) ? xl : xr;
    int col0 = (cb & 1) * 128;
    int row0 = blockIdx.x * 128;
    int t  = threadIdx.x;
    int tr = t >> 4, tc = t & 15;    // 16x16 thread grid
    float acc[8][8];
    #pragma unroll
    for (int i = 0; i < 8; ++i)
        #pragma unroll
        for (int j = 0; j < 8; ++j) acc[i][j] = 0.f;

    for (int k0 = 0; k0 < 256; k0 += TK) {
        #pragma unroll
        for (int h = 0; h < 2; ++h) {
            int f = h * 256 + t;             // float4 id, 512 total
            // A tile 128x16 -> transposed store
            int arow = f >> 2;               // 4 float4 per row
            int kk   = (f & 3) * 4;
            int gr   = row0 + arow;
            float4 a4 = (gr < M) ? *(const float4*)&A[(size_t)gr * NCH + k0 + kk]
                                 : make_float4(0.f, 0.f, 0.f, 0.f);
            Ast[kk + 0][arow] = a4.x;
            Ast[kk + 1][arow] = a4.y;
            Ast[kk + 2][arow] = a4.z;
            Ast[kk + 3][arow] = a4.w;
            // B tile 16x128
            int brow = f >> 5;               // 32 float4 per row
            int bc4  = (f & 31) * 4;
            float4 b4 = *(const float4*)&B[(size_t)(k0 + brow) * NCH + col0 + bc4];
            *(float4*)&Bs[brow][bc4] = b4;
        }
        __syncthreads();
        #pragma unroll
        for (int k = 0; k < TK; ++k) {
            float4 a0 = *(const float4*)&Ast[k][tr * 4];
            float4 a1 = *(const float4*)&Ast[k][64 + tr * 4];
            float4 b0 = *(const float4*)&Bs[k][tc * 4];
            float4 b1 = *(const float4*)&Bs[k][64 + tc * 4];
            float av[8] = {a0.x, a0.y, a0.z, a0.w, a1.x, a1.y, a1.z, a1.w};
            float bv[8] = {b0.x, b0.y, b0.z, b0.w, b1.x, b1.y, b1.z, b1.w};
            #pragma unroll
            for (int i = 0; i < 8; ++i)
                #pragma unroll
                for (int j = 0; j < 8; ++j)
                    acc[i][j] = fmaf(av[i], bv[j], acc[i][j]);
        }
        __syncthreads();
    }
    #pragma unroll
    for (int i = 0; i < 8; ++i) {
        int r = row0 + ((i < 4) ? (tr * 4 + i) : (64 + tr * 4 + (i - 4)));
        if (r >= M) continue;
        #pragma unroll
        for (int jb = 0; jb < 2; ++jb) {
            float4 v;
            v.x = acc[i][jb * 4 + 0];
            v.y = acc[i][jb * 4 + 1];
            v.z = acc[i][jb * 4 + 2];
            v.w = acc[i][jb * 4 + 3];
            int c = col0 + jb * 64 + tc * 4;
            *(float4*)&Out[(size_t)r * NCH + c] = v;
        }
    }
}

// ---------------------------------------------------------------------------
// Fused GAT aggregation: ONE pass over incoming edges per node.
//   out_i = (sum_j ex_j * xl_j) / (sum_j ex_j),  ex_j = exp(e_ij)
// (max-subtraction skipped: e is O(1) at these scales, fp32-exp safe; alpha
// identical mathematically).
// Wave per node; lane holds channels [4*lane,4*lane+4); lanes 0..31 = head0.
// Source indices are coalesced-loaded 64-at-a-time and shfl-broadcast;
// edge loop unrolled x2 for two independent gather chains.
// ---------------------------------------------------------------------------
__global__ __launch_bounds__(256) void gat_agg(
        const float* __restrict__ xl, const float* __restrict__ xr,
        const float* __restrict__ att, const float* __restrict__ bias,
        const int* __restrict__ offsets, const int* __restrict__ csr_src,
        float* __restrict__ hout, int nNodes) {
    int wid  = threadIdx.x >> 6;
    int lane = threadIdx.x & 63;
    int node = blockIdx.x * 4 + wid;
    if (node >= nNodes) return;
    int c0 = lane * 4;
    float4 att4 = *(const float4*)&att[c0];
    float4 xr4  = *(const float4*)&xr[(size_t)node * NCH + c0];
    int begin = offsets[node], end = offsets[node + 1];

    float denom = 0.f;
    float4 acc = make_float4(0.f, 0.f, 0.f, 0.f);

    for (int base = begin; base < end; base += 64) {
        int rem = end - base;
        int cnt = rem < 64 ? rem : 64;
        int sv  = (lane < rem) ? csr_src[base + lane] : 0;
        int j = 0;
        for (; j + 1 < cnt; j += 2) {
            int s0 = __shfl(sv, j, 64);
            int s1 = __shfl(sv, j + 1, 64);
            float4 xa = *(const float4*)&xl[(size_t)s0 * NCH + c0];
            float4 xb = *(const float4*)&xl[(size_t)s1 * NCH + c0];
            float mx, my, mz, mw, p0, p1;
            mx = xa.x + xr4.x; mx = mx > 0.f ? mx : LEAKY * mx;
            my = xa.y + xr4.y; my = my > 0.f ? my : LEAKY * my;
            mz = xa.z + xr4.z; mz = mz > 0.f ? mz : LEAKY * mz;
            mw = xa.w + xr4.w; mw = mw > 0.f ? mw : LEAKY * mw;
            p0 = mx * att4.x + my * att4.y + mz * att4.z + mw * att4.w;
            mx = xb.x + xr4.x; mx = mx > 0.f ? mx : LEAKY * mx;
            my = xb.y + xr4.y; my = my > 0.f ? my : LEAKY * my;
            mz = xb.z + xr4.z; mz = mz > 0.f ? mz : LEAKY * mz;
            mw = xb.w + xr4.w; mw = mw > 0.f ? mw : LEAKY * mw;
            p1 = mx * att4.x + my * att4.y + mz * att4.z + mw * att4.w;
            #pragma unroll
            for (int off = 16; off > 0; off >>= 1) {
                p0 += __shfl_xor(p0, off, 32);
                p1 += __shfl_xor(p1, off, 32);
            }
            float ex0 = expf(p0);
            float ex1 = expf(p1);
            denom += ex0 + ex1;
            acc.x = fmaf(ex0, xa.x, acc.x); acc.x = fmaf(ex1, xb.x, acc.x);
            acc.y = fmaf(ex0, xa.y, acc.y); acc.y = fmaf(ex1, xb.y, acc.y);
            acc.z = fmaf(ex0, xa.z, acc.z); acc.z = fmaf(ex1, xb.z, acc.z);
            acc.w = fmaf(ex0, xa.w, acc.w); acc.w = fmaf(ex1, xb.w, acc.w);
        }
        if (j < cnt) {
            int s0 = __shfl(sv, j, 64);
            float4 xa = *(const float4*)&xl[(size_t)s0 * NCH + c0];
            float mx = xa.x + xr4.x; mx = mx > 0.f ? mx : LEAKY * mx;
            float my = xa.y + xr4.y; my = my > 0.f ? my : LEAKY * my;
            float mz = xa.z + xr4.z; mz = mz > 0.f ? mz : LEAKY * mz;
            float mw = xa.w + xr4.w; mw = mw > 0.f ? mw : LEAKY * mw;
            float p0 = mx * att4.x + my * att4.y + mz * att4.z + mw * att4.w;
            #pragma unroll
            for (int off = 16; off > 0; off >>= 1) p0 += __shfl_xor(p0, off, 32);
            float ex0 = expf(p0);
            denom += ex0;
            acc.x = fmaf(ex0, xa.x, acc.x);
            acc.y = fmaf(ex0, xa.y, acc.y);
            acc.z = fmaf(ex0, xa.z, acc.z);
            acc.w = fmaf(ex0, xa.w, acc.w);
        }
    }
    float rd = 1.0f / denom;
    float4 b4 = *(const float4*)&bias[c0];
    float4 o;
    o.x = acc.x * rd + b4.x; o.x = o.x > 0.f ? o.x : 0.f;
    o.y = acc.y * rd + b4.y; o.y = o.y > 0.f ? o.y : 0.f;
    o.z = acc.z * rd + b4.z; o.z = o.z > 0.f ? o.z : 0.f;
    o.w = acc.w * rd + b4.w; o.w = o.w > 0.f ? o.w : 0.f;
    *(float4*)&hout[(size_t)node * NCH + c0] = o;
}

// ---------------------------------------------------------------------------
// Final projection: out = h @ Wout[256,4] + bout. Wave per node.
// ---------------------------------------------------------------------------
__global__ __launch_bounds__(256) void out_gemm(
        const float* __restrict__ h, const float* __restrict__ Wout,
        const float* __restrict__ bout, float* __restrict__ out, int nNodes) {
    int wid  = threadIdx.x >> 6;
    int lane = threadIdx.x & 63;
    int node = blockIdx.x * 4 + wid;
    if (node >= nNodes) return;
    int c0 = lane * 4;
    float4 h4 = *(const float4*)&h[(size_t)node * NCH + c0];
    float hv[4] = {h4.x, h4.y, h4.z, h4.w};
    float p0 = 0.f, p1 = 0.f, p2 = 0.f, p3 = 0.f;
    #pragma unroll
    for (int j = 0; j < 4; ++j) {
        float4 w4 = *(const float4*)&Wout[(size_t)(c0 + j) * 4];
        p0 = fmaf(hv[j], w4.x, p0);
        p1 = fmaf(hv[j], w4.y, p1);
        p2 = fmaf(hv[j], w4.z, p2);
        p3 = fmaf(hv[j], w4.w, p3);
    }
    #pragma unroll
    for (int off = 32; off > 0; off >>= 1) {
        p0 += __shfl_xor(p0, off, 64);
        p1 += __shfl_xor(p1, off, 64);
        p2 += __shfl_xor(p2, off, 64);
        p3 += __shfl_xor(p3, off, 64);
    }
    if (lane == 0) {
        out[(size_t)node * 4 + 0] = p0 + bout[0];
        out[(size_t)node * 4 + 1] = p1 + bout[1];
        out[(size_t)node * 4 + 2] = p2 + bout[2];
        out[(size_t)node * 4 + 3] = p3 + bout[3];
    }
}

// ---------------------------------------------------------------------------
extern "C" void kernel_launch(void* const* d_in, const int* in_sizes, int n_in,
                              void* d_out, int out_size, void* d_ws, size_t ws_size,
                              hipStream_t stream) {
    const float* x  = (const float*)d_in[0];
    const int*   ei = (const int*)d_in[1];
    const float* Wl[3]  = {(const float*)d_in[2], (const float*)d_in[6],  (const float*)d_in[10]};
    const float* Wr[3]  = {(const float*)d_in[3], (const float*)d_in[7],  (const float*)d_in[11]};
    const float* att[3] = {(const float*)d_in[4], (const float*)d_in[8],  (const float*)d_in[12]};
    const float* bb[3]  = {(const float*)d_in[5], (const float*)d_in[9],  (const float*)d_in[13]};
    const float* Wout = (const float*)d_in[14];
    const float* bout = (const float*)d_in[15];

    int Nn   = in_sizes[0] / NCH;       // 20000
    int E    = in_sizes[1] / 2;         // 320000
    int Etot = E + Nn;                  // + self loops

    // workspace layout (all fp32 arrays first, 16B aligned)
    size_t NEf = (size_t)Nn * NCH;
    float* xl     = (float*)d_ws;
    float* xr     = xl + NEf;
    float* hA     = xr + NEf;
    float* hB     = hA + NEf;
    int*   counts  = (int*)(hB + NEf);
    int*   offsets = counts + Nn;                // Nn+1
    int*   cursor  = offsets + (Nn + 1);
    int*   csr_src = cursor + Nn;                // Etot

    // CSR build (by dst)
    hipMemsetAsync(counts, 0, (size_t)Nn * sizeof(int), stream);
    int ethreads = (Etot + 255) / 256;
    count_kernel<<<ethreads, 256, 0, stream>>>(ei, E, Nn, counts);
    scan_kernel<<<1, 1024, 0, stream>>>(counts, offsets, cursor, Nn);
    scatter_kernel<<<ethreads, 256, 0, stream>>>(ei, E, Nn, cursor, csr_src);

    dim3 ggrid((Nn + 127) / 128, 4);
    int  ngrid = (Nn + 3) / 4;

    const float* in = x;
    float* houts[3] = {hA, hB, hA};
    for (int l = 0; l < 3; ++l) {
        dual_gemm<<<ggrid, 256, 0, stream>>>(in, Wl[l], Wr[l], xl, xr, Nn);
        gat_agg<<<ngrid, 256, 0, stream>>>(xl, xr, att[l], bb[l],
                                           offsets, csr_src, houts[l], Nn);
        in = houts[l];
    }
    out_gemm<<<ngrid, 256, 0, stream>>>(in, Wout, bout, (float*)d_out, Nn);
}

// Round 3
// 308.821 us; speedup vs baseline: 1.9672x; 1.4206x over previous
//
#include <hip/hip_runtime.h>
#include <hip/hip_bf16.h>
#include <math.h>

// N=20000, E=320000, layers: [N,256]@[256,256] GEMMs, HEADS=2, HID=128.
#define NCH 256
#define LEAKY 0.2f

typedef __attribute__((ext_vector_type(8))) short bf16x8;  // 4 VGPRs
typedef __attribute__((ext_vector_type(4))) float f32x4;   // MFMA C/D

static __device__ __forceinline__ ushort f2bf(float f) {
    unsigned u = __float_as_uint(f);
    u += 0x7fffu + ((u >> 16) & 1u);          // RNE
    return (ushort)(u >> 16);
}
static __device__ __forceinline__ float bf2f(ushort h) {
    return __uint_as_float(((unsigned)h) << 16);
}

// ---------------------------------------------------------------------------
// CSR build: counts -> scan -> scatter
// ---------------------------------------------------------------------------
__global__ void count_kernel(const int* __restrict__ ei, int E, int n,
                             int* __restrict__ counts) {
    int tid = blockIdx.x * 256 + threadIdx.x;
    int tot = E + n;
    if (tid >= tot) return;
    int dst = (tid < E) ? ei[E + tid] : (tid - E);
    atomicAdd(&counts[dst], 1);
}

__global__ void scan_kernel(const int* __restrict__ counts,
                            int* __restrict__ offsets,
                            int* __restrict__ cursor, int n) {
    __shared__ int wsum[16];
    int tid  = threadIdx.x;          // 1024 threads = 16 waves
    int lane = tid & 63, w = tid >> 6;
    int carry = 0;
    for (int base = 0; base < n; base += 1024) {
        int idx = base + tid;
        int v = (idx < n) ? counts[idx] : 0;
        int incl = v;
        #pragma unroll
        for (int off = 1; off < 64; off <<= 1) {
            int t2 = __shfl_up(incl, off, 64);
            if (lane >= off) incl += t2;
        }
        if (lane == 63) wsum[w] = incl;
        __syncthreads();
        if (w == 0 && lane < 16) {
            int s = wsum[lane];
            #pragma unroll
            for (int off = 1; off < 16; off <<= 1) {
                int t2 = __shfl_up(s, off, 64);
                if (lane >= off) s += t2;
            }
            wsum[lane] = s;
        }
        __syncthreads();
        int wpre = (w == 0) ? 0 : wsum[w - 1];
        int excl = carry + wpre + incl - v;
        if (idx < n) { offsets[idx] = excl; cursor[idx] = excl; }
        carry += wsum[15];
        __syncthreads();
    }
    if (tid == 0) offsets[n] = carry;
}

__global__ void scatter_kernel(const int* __restrict__ ei, int E, int n,
                               int* __restrict__ cursor,
                               int* __restrict__ csr_src) {
    int tid = blockIdx.x * 256 + threadIdx.x;
    int tot = E + n;
    if (tid >= tot) return;
    int src, dst;
    if (tid < E) { src = ei[tid]; dst = ei[E + tid]; }
    else         { src = dst = tid - E; }
    int pos = atomicAdd(&cursor[dst], 1);
    csr_src[pos] = src;
}

// ---------------------------------------------------------------------------
// fp32 -> bf16 hi/lo split (for the harness-provided x only)
// ---------------------------------------------------------------------------
__global__ void split_kernel(const float* __restrict__ in,
                             ushort* __restrict__ hi, ushort* __restrict__ lo,
                             int n4) {
    int i = blockIdx.x * 256 + threadIdx.x;
    if (i >= n4) return;
    float4 v = ((const float4*)in)[i];
    ushort h0 = f2bf(v.x), h1 = f2bf(v.y), h2 = f2bf(v.z), h3 = f2bf(v.w);
    ((ushort4*)hi)[i] = make_ushort4(h0, h1, h2, h3);
    ((ushort4*)lo)[i] = make_ushort4(f2bf(v.x - bf2f(h0)), f2bf(v.y - bf2f(h1)),
                                     f2bf(v.z - bf2f(h2)), f2bf(v.w - bf2f(h3)));
}

// ---------------------------------------------------------------------------
// Weight transpose+split: W[256,256] (k-major) -> Wt[256,256] (n-major,k-contig)
// as bf16 hi/lo. All 6 matrices in one dispatch (grid.z).
// ---------------------------------------------------------------------------
struct WPtrs { const float* w[6]; };
__global__ __launch_bounds__(1024) void wsplit_kernel(WPtrs p,
        ushort* __restrict__ hi, ushort* __restrict__ lo) {
    __shared__ float tile[32][33];
    int m = blockIdx.z;
    const float* W = p.w[m];
    size_t base = (size_t)m * 65536;
    int k = blockIdx.y * 32 + threadIdx.y;
    int n = blockIdx.x * 32 + threadIdx.x;
    tile[threadIdx.y][threadIdx.x] = W[k * NCH + n];
    __syncthreads();
    int on = blockIdx.x * 32 + threadIdx.y;   // out row = n
    int ok = blockIdx.y * 32 + threadIdx.x;   // out col = k
    float v = tile[threadIdx.x][threadIdx.y];
    ushort h = f2bf(v);
    hi[base + (size_t)on * NCH + ok] = h;
    lo[base + (size_t)on * NCH + ok] = f2bf(v - bf2f(h));
}

// ---------------------------------------------------------------------------
// MFMA dual GEMM with bf16 hi/lo split (3-product fp32-accurate).
// A (hi/lo bf16, [M][256] k-contig), Bt (hi/lo bf16, [2][256][256] n-major).
// Block: 256 thr = 4 waves, 128x128 tile; wave -> 64x64 (4x4 frags 16x16x32).
// LDS layout [outdim][k] padded to LDK=40 -> ds_read_b128 frags, <=2-way banks.
// grid.y: 0,1 -> Wl cols 0/128 -> xl ; 2,3 -> Wr -> xr.
// ---------------------------------------------------------------------------
#define LDK 40
__global__ __launch_bounds__(256) void dual_gemm_mfma(
        const ushort* __restrict__ Ahi, const ushort* __restrict__ Alo,
        const ushort* __restrict__ Bthi, const ushort* __restrict__ Btlo,
        float* __restrict__ xl, float* __restrict__ xr, int M) {
    __shared__ ushort As[2][128 * LDK];
    __shared__ ushort Bs[2][128 * LDK];
    int cb = blockIdx.y;
    const ushort* Bh = Bthi + (size_t)(cb >> 1) * 65536;
    const ushort* Bl = Btlo + (size_t)(cb >> 1) * 65536;
    float* Out = (cb < 2) ? xl : xr;
    int col0 = (cb & 1) * 128;
    int row0 = blockIdx.x * 128;
    int t = threadIdx.x;
    int lane = t & 63, w = t >> 6;
    int wr = w >> 1, wc = w & 1;
    int l15 = lane & 15, l4 = lane >> 4;

    f32x4 acc[4][4];
    #pragma unroll
    for (int i = 0; i < 4; ++i)
        #pragma unroll
        for (int j = 0; j < 4; ++j) acc[i][j] = (f32x4){0.f, 0.f, 0.f, 0.f};

    // staging: 512 16B-chunks per tile array; thread t handles chunks t, t+256
    int r0 = t >> 2,          q0 = (t & 3) * 8;
    int r1 = (t + 256) >> 2,  q1 = ((t + 256) & 3) * 8;

    for (int k0 = 0; k0 < 256; k0 += 32) {
        uint4 z = make_uint4(0, 0, 0, 0);
        uint4 a0h = z, a0l = z, a1h = z, a1l = z;
        if (row0 + r0 < M) {
            a0h = *(const uint4*)&Ahi[(size_t)(row0 + r0) * NCH + k0 + q0];
            a0l = *(const uint4*)&Alo[(size_t)(row0 + r0) * NCH + k0 + q0];
        }
        if (row0 + r1 < M) {
            a1h = *(const uint4*)&Ahi[(size_t)(row0 + r1) * NCH + k0 + q1];
            a1l = *(const uint4*)&Alo[(size_t)(row0 + r1) * NCH + k0 + q1];
        }
        uint4 b0h = *(const uint4*)&Bh[(size_t)(col0 + r0) * NCH + k0 + q0];
        uint4 b0l = *(const uint4*)&Bl[(size_t)(col0 + r0) * NCH + k0 + q0];
        uint4 b1h = *(const uint4*)&Bh[(size_t)(col0 + r1) * NCH + k0 + q1];
        uint4 b1l = *(const uint4*)&Bl[(size_t)(col0 + r1) * NCH + k0 + q1];
        __syncthreads();              // previous tile fully consumed
        *(uint4*)&As[0][r0 * LDK + q0] = a0h;
        *(uint4*)&As[1][r0 * LDK + q0] = a0l;
        *(uint4*)&As[0][r1 * LDK + q1] = a1h;
        *(uint4*)&As[1][r1 * LDK + q1] = a1l;
        *(uint4*)&Bs[0][r0 * LDK + q0] = b0h;
        *(uint4*)&Bs[1][r0 * LDK + q0] = b0l;
        *(uint4*)&Bs[0][r1 * LDK + q1] = b1h;
        *(uint4*)&Bs[1][r1 * LDK + q1] = b1l;
        __syncthreads();

        bf16x8 af[4][2], bq[4][2];
        #pragma unroll
        for (int fm = 0; fm < 4; ++fm) {
            int addr = (wr * 64 + fm * 16 + l15) * LDK + l4 * 8;
            af[fm][0] = *(const bf16x8*)&As[0][addr];
            af[fm][1] = *(const bf16x8*)&As[1][addr];
        }
        #pragma unroll
        for (int fn = 0; fn < 4; ++fn) {
            int addr = (wc * 64 + fn * 16 + l15) * LDK + l4 * 8;
            bq[fn][0] = *(const bf16x8*)&Bs[0][addr];
            bq[fn][1] = *(const bf16x8*)&Bs[1][addr];
        }
        #pragma unroll
        for (int fm = 0; fm < 4; ++fm)
            #pragma unroll
            for (int fn = 0; fn < 4; ++fn) {
                acc[fm][fn] = __builtin_amdgcn_mfma_f32_16x16x32_bf16(
                    af[fm][0], bq[fn][0], acc[fm][fn], 0, 0, 0);
                acc[fm][fn] = __builtin_amdgcn_mfma_f32_16x16x32_bf16(
                    af[fm][0], bq[fn][1], acc[fm][fn], 0, 0, 0);
                acc[fm][fn] = __builtin_amdgcn_mfma_f32_16x16x32_bf16(
                    af[fm][1], bq[fn][0], acc[fm][fn], 0, 0, 0);
            }
    }

    // C/D layout: col = lane&15, row = (lane>>4)*4 + r
    #pragma unroll
    for (int fm = 0; fm < 4; ++fm)
        #pragma unroll
        for (int fn = 0; fn < 4; ++fn) {
            int col = col0 + wc * 64 + fn * 16 + l15;
            #pragma unroll
            for (int r = 0; r < 4; ++r) {
                int row = row0 + wr * 64 + fm * 16 + l4 * 4 + r;
                if (row < M) Out[(size_t)row * NCH + col] = acc[fm][fn][r];
            }
        }
}

// ---------------------------------------------------------------------------
// Fused GAT aggregation (one pass), writes next-layer input as bf16 hi/lo.
// Wave per node; lane holds channels [4*lane,4*lane+4); lanes 0..31 = head0.
// ---------------------------------------------------------------------------
__global__ __launch_bounds__(256) void gat_agg(
        const float* __restrict__ xl, const float* __restrict__ xr,
        const float* __restrict__ att, const float* __restrict__ bias,
        const int* __restrict__ offsets, const int* __restrict__ csr_src,
        ushort* __restrict__ hhi, ushort* __restrict__ hlo, int nNodes) {
    int wid  = threadIdx.x >> 6;
    int lane = threadIdx.x & 63;
    int node = blockIdx.x * 4 + wid;
    if (node >= nNodes) return;
    int c0 = lane * 4;
    float4 att4 = *(const float4*)&att[c0];
    float4 xr4  = *(const float4*)&xr[(size_t)node * NCH + c0];
    int begin = offsets[node], end = offsets[node + 1];

    float denom = 0.f;
    float4 acc = make_float4(0.f, 0.f, 0.f, 0.f);

    for (int base = begin; base < end; base += 64) {
        int rem = end - base;
        int cnt = rem < 64 ? rem : 64;
        int sv  = (lane < rem) ? csr_src[base + lane] : 0;
        int j = 0;
        for (; j + 1 < cnt; j += 2) {
            int s0 = __shfl(sv, j, 64);
            int s1 = __shfl(sv, j + 1, 64);
            float4 xa = *(const float4*)&xl[(size_t)s0 * NCH + c0];
            float4 xb = *(const float4*)&xl[(size_t)s1 * NCH + c0];
            float mx, my, mz, mw, p0, p1;
            mx = xa.x + xr4.x; mx = mx > 0.f ? mx : LEAKY * mx;
            my = xa.y + xr4.y; my = my > 0.f ? my : LEAKY * my;
            mz = xa.z + xr4.z; mz = mz > 0.f ? mz : LEAKY * mz;
            mw = xa.w + xr4.w; mw = mw > 0.f ? mw : LEAKY * mw;
            p0 = mx * att4.x + my * att4.y + mz * att4.z + mw * att4.w;
            mx = xb.x + xr4.x; mx = mx > 0.f ? mx : LEAKY * mx;
            my = xb.y + xr4.y; my = my > 0.f ? my : LEAKY * my;
            mz = xb.z + xr4.z; mz = mz > 0.f ? mz : LEAKY * mz;
            mw = xb.w + xr4.w; mw = mw > 0.f ? mw : LEAKY * mw;
            p1 = mx * att4.x + my * att4.y + mz * att4.z + mw * att4.w;
            #pragma unroll
            for (int off = 16; off > 0; off >>= 1) {
                p0 += __shfl_xor(p0, off, 32);
                p1 += __shfl_xor(p1, off, 32);
            }
            float ex0 = expf(p0);
            float ex1 = expf(p1);
            denom += ex0 + ex1;
            acc.x = fmaf(ex0, xa.x, acc.x); acc.x = fmaf(ex1, xb.x, acc.x);
            acc.y = fmaf(ex0, xa.y, acc.y); acc.y = fmaf(ex1, xb.y, acc.y);
            acc.z = fmaf(ex0, xa.z, acc.z); acc.z = fmaf(ex1, xb.z, acc.z);
            acc.w = fmaf(ex0, xa.w, acc.w); acc.w = fmaf(ex1, xb.w, acc.w);
        }
        if (j < cnt) {
            int s0 = __shfl(sv, j, 64);
            float4 xa = *(const float4*)&xl[(size_t)s0 * NCH + c0];
            float mx = xa.x + xr4.x; mx = mx > 0.f ? mx : LEAKY * mx;
            float my = xa.y + xr4.y; my = my > 0.f ? my : LEAKY * my;
            float mz = xa.z + xr4.z; mz = mz > 0.f ? mz : LEAKY * mz;
            float mw = xa.w + xr4.w; mw = mw > 0.f ? mw : LEAKY * mw;
            float p0 = mx * att4.x + my * att4.y + mz * att4.z + mw * att4.w;
            #pragma unroll
            for (int off = 16; off > 0; off >>= 1) p0 += __shfl_xor(p0, off, 32);
            float ex0 = expf(p0);
            denom += ex0;
            acc.x = fmaf(ex0, xa.x, acc.x);
            acc.y = fmaf(ex0, xa.y, acc.y);
            acc.z = fmaf(ex0, xa.z, acc.z);
            acc.w = fmaf(ex0, xa.w, acc.w);
        }
    }
    float rd = 1.0f / denom;
    float4 b4 = *(const float4*)&bias[c0];
    float ox = fmaxf(acc.x * rd + b4.x, 0.f);
    float oy = fmaxf(acc.y * rd + b4.y, 0.f);
    float oz = fmaxf(acc.z * rd + b4.z, 0.f);
    float ow = fmaxf(acc.w * rd + b4.w, 0.f);
    ushort hx = f2bf(ox), hy = f2bf(oy), hz = f2bf(oz), hw = f2bf(ow);
    *(ushort4*)&hhi[(size_t)node * NCH + c0] = make_ushort4(hx, hy, hz, hw);
    *(ushort4*)&hlo[(size_t)node * NCH + c0] =
        make_ushort4(f2bf(ox - bf2f(hx)), f2bf(oy - bf2f(hy)),
                     f2bf(oz - bf2f(hz)), f2bf(ow - bf2f(hw)));
}

// ---------------------------------------------------------------------------
// Final projection from hi/lo bf16 h: out = h @ Wout[256,4] + bout.
// ---------------------------------------------------------------------------
__global__ __launch_bounds__(256) void out_gemm(
        const ushort* __restrict__ hhi, const ushort* __restrict__ hlo,
        const float* __restrict__ Wout,
        const float* __restrict__ bout, float* __restrict__ out, int nNodes) {
    int wid  = threadIdx.x >> 6;
    int lane = threadIdx.x & 63;
    int node = blockIdx.x * 4 + wid;
    if (node >= nNodes) return;
    int c0 = lane * 4;
    ushort4 hh = *(const ushort4*)&hhi[(size_t)node * NCH + c0];
    ushort4 hl = *(const ushort4*)&hlo[(size_t)node * NCH + c0];
    float hv[4] = {bf2f(hh.x) + bf2f(hl.x), bf2f(hh.y) + bf2f(hl.y),
                   bf2f(hh.z) + bf2f(hl.z), bf2f(hh.w) + bf2f(hl.w)};
    float p0 = 0.f, p1 = 0.f, p2 = 0.f, p3 = 0.f;
    #pragma unroll
    for (int j = 0; j < 4; ++j) {
        float4 w4 = *(const float4*)&Wout[(size_t)(c0 + j) * 4];
        p0 = fmaf(hv[j], w4.x, p0);
        p1 = fmaf(hv[j], w4.y, p1);
        p2 = fmaf(hv[j], w4.z, p2);
        p3 = fmaf(hv[j], w4.w, p3);
    }
    #pragma unroll
    for (int off = 32; off > 0; off >>= 1) {
        p0 += __shfl_xor(p0, off, 64);
        p1 += __shfl_xor(p1, off, 64);
        p2 += __shfl_xor(p2, off, 64);
        p3 += __shfl_xor(p3, off, 64);
    }
    if (lane == 0) {
        out[(size_t)node * 4 + 0] = p0 + bout[0];
        out[(size_t)node * 4 + 1] = p1 + bout[1];
        out[(size_t)node * 4 + 2] = p2 + bout[2];
        out[(size_t)node * 4 + 3] = p3 + bout[3];
    }
}

// ---------------------------------------------------------------------------
extern "C" void kernel_launch(void* const* d_in, const int* in_sizes, int n_in,
                              void* d_out, int out_size, void* d_ws, size_t ws_size,
                              hipStream_t stream) {
    const float* x  = (const float*)d_in[0];
    const int*   ei = (const int*)d_in[1];
    const float* Wl[3]  = {(const float*)d_in[2], (const float*)d_in[6],  (const float*)d_in[10]};
    const float* Wr[3]  = {(const float*)d_in[3], (const float*)d_in[7],  (const float*)d_in[11]};
    const float* att[3] = {(const float*)d_in[4], (const float*)d_in[8],  (const float*)d_in[12]};
    const float* bb[3]  = {(const float*)d_in[5], (const float*)d_in[9],  (const float*)d_in[13]};
    const float* Wout = (const float*)d_in[14];
    const float* bout = (const float*)d_in[15];

    int Nn   = in_sizes[0] / NCH;       // 20000
    int E    = in_sizes[1] / 2;         // 320000
    int Etot = E + Nn;

    // workspace layout (16B-aligned throughout)
    size_t NEf = (size_t)Nn * NCH;      // 5.12M elements
    float*  xl   = (float*)d_ws;
    float*  xr   = xl + NEf;
    ushort* pAhi = (ushort*)(xr + NEf);
    ushort* pAlo = pAhi + NEf;
    ushort* pBhi = pAlo + NEf;
    ushort* pBlo = pBhi + NEf;
    ushort* wthi = pBlo + NEf;                 // 6 * 65536
    ushort* wtlo = wthi + 6 * 65536;
    int*   counts  = (int*)(wtlo + 6 * 65536);
    int*   offsets = counts + Nn;
    int*   cursor  = offsets + (Nn + 1);
    int*   csr_src = cursor + Nn;

    // CSR build (by dst)
    hipMemsetAsync(counts, 0, (size_t)Nn * sizeof(int), stream);
    int eblocks = (Etot + 255) / 256;
    count_kernel<<<eblocks, 256, 0, stream>>>(ei, E, Nn, counts);
    scan_kernel<<<1, 1024, 0, stream>>>(counts, offsets, cursor, Nn);
    scatter_kernel<<<eblocks, 256, 0, stream>>>(ei, E, Nn, cursor, csr_src);

    // weights: transpose + split (all 6 at once)
    WPtrs wp = {{Wl[0], Wr[0], Wl[1], Wr[1], Wl[2], Wr[2]}};
    wsplit_kernel<<<dim3(8, 8, 6), dim3(32, 32), 0, stream>>>(wp, wthi, wtlo);

    // x -> bf16 hi/lo
    int n4 = (int)(NEf / 4);
    split_kernel<<<(n4 + 255) / 256, 256, 0, stream>>>(x, pAhi, pAlo, n4);

    dim3 ggrid((Nn + 127) / 128, 4);
    int  ngrid = (Nn + 3) / 4;

    // ping-pong: L1 A=pA out->pB; L2 A=pB out->pA; L3 A=pA out->pB
    ushort* curHi = pAhi; ushort* curLo = pAlo;
    ushort* nxtHi = pBhi; ushort* nxtLo = pBlo;
    for (int l = 0; l < 3; ++l) {
        dual_gemm_mfma<<<ggrid, 256, 0, stream>>>(
            curHi, curLo, wthi + (size_t)l * 2 * 65536, wtlo + (size_t)l * 2 * 65536,
            xl, xr, Nn);
        gat_agg<<<ngrid, 256, 0, stream>>>(xl, xr, att[l], bb[l],
                                           offsets, csr_src, nxtHi, nxtLo, Nn);
        ushort* th = curHi; ushort* tl = curLo;
        curHi = nxtHi; curLo = nxtLo; nxtHi = th; nxtLo = tl;
    }
    out_gemm<<<ngrid, 256, 0, stream>>>(curHi, curLo, Wout, bout, (float*)d_out, Nn);
}

// Round 4
// 305.184 us; speedup vs baseline: 1.9907x; 1.0119x over previous
//
#include <hip/hip_runtime.h>
#include <hip/hip_bf16.h>
#include <math.h>

// N=20000, E=320000, layers: [N,256]@[256,256] GEMMs, HEADS=2, HID=128.
#define NCH 256
#define LEAKY 0.2f

typedef __attribute__((ext_vector_type(8))) short bf16x8;  // 4 VGPRs
typedef __attribute__((ext_vector_type(4))) float f32x4;   // MFMA C/D

static __device__ __forceinline__ ushort f2bf(float f) {
    unsigned u = __float_as_uint(f);
    u += 0x7fffu + ((u >> 16) & 1u);          // RNE
    return (ushort)(u >> 16);
}
static __device__ __forceinline__ float bf2f(ushort h) {
    return __uint_as_float(((unsigned)h) << 16);
}

// ---------------------------------------------------------------------------
// CSR build: counts -> scan -> scatter
// ---------------------------------------------------------------------------
__global__ void count_kernel(const int* __restrict__ ei, int E, int n,
                             int* __restrict__ counts) {
    int tid = blockIdx.x * 256 + threadIdx.x;
    int tot = E + n;
    if (tid >= tot) return;
    int dst = (tid < E) ? ei[E + tid] : (tid - E);
    atomicAdd(&counts[dst], 1);
}

__global__ void scan_kernel(const int* __restrict__ counts,
                            int* __restrict__ offsets,
                            int* __restrict__ cursor, int n) {
    __shared__ int wsum[16];
    int tid  = threadIdx.x;          // 1024 threads = 16 waves
    int lane = tid & 63, w = tid >> 6;
    int carry = 0;
    for (int base = 0; base < n; base += 1024) {
        int idx = base + tid;
        int v = (idx < n) ? counts[idx] : 0;
        int incl = v;
        #pragma unroll
        for (int off = 1; off < 64; off <<= 1) {
            int t2 = __shfl_up(incl, off, 64);
            if (lane >= off) incl += t2;
        }
        if (lane == 63) wsum[w] = incl;
        __syncthreads();
        if (w == 0 && lane < 16) {
            int s = wsum[lane];
            #pragma unroll
            for (int off = 1; off < 16; off <<= 1) {
                int t2 = __shfl_up(s, off, 64);
                if (lane >= off) s += t2;
            }
            wsum[lane] = s;
        }
        __syncthreads();
        int wpre = (w == 0) ? 0 : wsum[w - 1];
        int excl = carry + wpre + incl - v;
        if (idx < n) { offsets[idx] = excl; cursor[idx] = excl; }
        carry += wsum[15];
        __syncthreads();
    }
    if (tid == 0) offsets[n] = carry;
}

__global__ void scatter_kernel(const int* __restrict__ ei, int E, int n,
                               int* __restrict__ cursor,
                               int* __restrict__ csr_src) {
    int tid = blockIdx.x * 256 + threadIdx.x;
    int tot = E + n;
    if (tid >= tot) return;
    int src, dst;
    if (tid < E) { src = ei[tid]; dst = ei[E + tid]; }
    else         { src = dst = tid - E; }
    int pos = atomicAdd(&cursor[dst], 1);
    csr_src[pos] = src;
}

// ---------------------------------------------------------------------------
// fp32 -> bf16 hi/lo split (layer-1 input x only)
// ---------------------------------------------------------------------------
__global__ void split_kernel(const float* __restrict__ in,
                             ushort* __restrict__ hi, ushort* __restrict__ lo,
                             int n4) {
    int i = blockIdx.x * 256 + threadIdx.x;
    if (i >= n4) return;
    float4 v = ((const float4*)in)[i];
    ushort h0 = f2bf(v.x), h1 = f2bf(v.y), h2 = f2bf(v.z), h3 = f2bf(v.w);
    ((ushort4*)hi)[i] = make_ushort4(h0, h1, h2, h3);
    ((ushort4*)lo)[i] = make_ushort4(f2bf(v.x - bf2f(h0)), f2bf(v.y - bf2f(h1)),
                                     f2bf(v.z - bf2f(h2)), f2bf(v.w - bf2f(h3)));
}

// ---------------------------------------------------------------------------
// Weight transpose+split: W[256,256] -> Wt[256,256] (n-major) bf16 hi/lo.
// ---------------------------------------------------------------------------
struct WPtrs { const float* w[6]; };
__global__ __launch_bounds__(1024) void wsplit_kernel(WPtrs p,
        ushort* __restrict__ hi, ushort* __restrict__ lo) {
    __shared__ float tile[32][33];
    int m = blockIdx.z;
    const float* W = p.w[m];
    size_t base = (size_t)m * 65536;
    int k = blockIdx.y * 32 + threadIdx.y;
    int n = blockIdx.x * 32 + threadIdx.x;
    tile[threadIdx.y][threadIdx.x] = W[k * NCH + n];
    __syncthreads();
    int on = blockIdx.x * 32 + threadIdx.y;
    int ok = blockIdx.y * 32 + threadIdx.x;
    float v = tile[threadIdx.x][threadIdx.y];
    ushort h = f2bf(v);
    hi[base + (size_t)on * NCH + ok] = h;
    lo[base + (size_t)on * NCH + ok] = f2bf(v - bf2f(h));
}

// ---------------------------------------------------------------------------
// MFMA dual GEMM with bf16 hi/lo split (3-product fp32-accurate).
// ---------------------------------------------------------------------------
#define LDK 40
__global__ __launch_bounds__(256) void dual_gemm_mfma(
        const ushort* __restrict__ Ahi, const ushort* __restrict__ Alo,
        const ushort* __restrict__ Bthi, const ushort* __restrict__ Btlo,
        float* __restrict__ xl, float* __restrict__ xr, int M) {
    __shared__ ushort As[2][128 * LDK];
    __shared__ ushort Bs[2][128 * LDK];
    int cb = blockIdx.y;
    const ushort* Bh = Bthi + (size_t)(cb >> 1) * 65536;
    const ushort* Bl = Btlo + (size_t)(cb >> 1) * 65536;
    float* Out = (cb < 2) ? xl : xr;
    int col0 = (cb & 1) * 128;
    int row0 = blockIdx.x * 128;
    int t = threadIdx.x;
    int lane = t & 63, w = t >> 6;
    int wr = w >> 1, wc = w & 1;
    int l15 = lane & 15, l4 = lane >> 4;

    f32x4 acc[4][4];
    #pragma unroll
    for (int i = 0; i < 4; ++i)
        #pragma unroll
        for (int j = 0; j < 4; ++j) acc[i][j] = (f32x4){0.f, 0.f, 0.f, 0.f};

    int r0 = t >> 2,          q0 = (t & 3) * 8;
    int r1 = (t + 256) >> 2,  q1 = ((t + 256) & 3) * 8;

    for (int k0 = 0; k0 < 256; k0 += 32) {
        uint4 z = make_uint4(0, 0, 0, 0);
        uint4 a0h = z, a0l = z, a1h = z, a1l = z;
        if (row0 + r0 < M) {
            a0h = *(const uint4*)&Ahi[(size_t)(row0 + r0) * NCH + k0 + q0];
            a0l = *(const uint4*)&Alo[(size_t)(row0 + r0) * NCH + k0 + q0];
        }
        if (row0 + r1 < M) {
            a1h = *(const uint4*)&Ahi[(size_t)(row0 + r1) * NCH + k0 + q1];
            a1l = *(const uint4*)&Alo[(size_t)(row0 + r1) * NCH + k0 + q1];
        }
        uint4 b0h = *(const uint4*)&Bh[(size_t)(col0 + r0) * NCH + k0 + q0];
        uint4 b0l = *(const uint4*)&Bl[(size_t)(col0 + r0) * NCH + k0 + q0];
        uint4 b1h = *(const uint4*)&Bh[(size_t)(col0 + r1) * NCH + k0 + q1];
        uint4 b1l = *(const uint4*)&Bl[(size_t)(col0 + r1) * NCH + k0 + q1];
        __syncthreads();
        *(uint4*)&As[0][r0 * LDK + q0] = a0h;
        *(uint4*)&As[1][r0 * LDK + q0] = a0l;
        *(uint4*)&As[0][r1 * LDK + q1] = a1h;
        *(uint4*)&As[1][r1 * LDK + q1] = a1l;
        *(uint4*)&Bs[0][r0 * LDK + q0] = b0h;
        *(uint4*)&Bs[1][r0 * LDK + q0] = b0l;
        *(uint4*)&Bs[0][r1 * LDK + q1] = b1h;
        *(uint4*)&Bs[1][r1 * LDK + q1] = b1l;
        __syncthreads();

        bf16x8 af[4][2], bq[4][2];
        #pragma unroll
        for (int fm = 0; fm < 4; ++fm) {
            int addr = (wr * 64 + fm * 16 + l15) * LDK + l4 * 8;
            af[fm][0] = *(const bf16x8*)&As[0][addr];
            af[fm][1] = *(const bf16x8*)&As[1][addr];
        }
        #pragma unroll
        for (int fn = 0; fn < 4; ++fn) {
            int addr = (wc * 64 + fn * 16 + l15) * LDK + l4 * 8;
            bq[fn][0] = *(const bf16x8*)&Bs[0][addr];
            bq[fn][1] = *(const bf16x8*)&Bs[1][addr];
        }
        #pragma unroll
        for (int fm = 0; fm < 4; ++fm)
            #pragma unroll
            for (int fn = 0; fn < 4; ++fn) {
                acc[fm][fn] = __builtin_amdgcn_mfma_f32_16x16x32_bf16(
                    af[fm][0], bq[fn][0], acc[fm][fn], 0, 0, 0);
                acc[fm][fn] = __builtin_amdgcn_mfma_f32_16x16x32_bf16(
                    af[fm][0], bq[fn][1], acc[fm][fn], 0, 0, 0);
                acc[fm][fn] = __builtin_amdgcn_mfma_f32_16x16x32_bf16(
                    af[fm][1], bq[fn][0], acc[fm][fn], 0, 0, 0);
            }
    }

    #pragma unroll
    for (int fm = 0; fm < 4; ++fm)
        #pragma unroll
        for (int fn = 0; fn < 4; ++fn) {
            int col = col0 + wc * 64 + fn * 16 + l15;
            #pragma unroll
            for (int r = 0; r < 4; ++r) {
                int row = row0 + wr * 64 + fm * 16 + l4 * 4 + r;
                if (row < M) Out[(size_t)row * NCH + col] = acc[fm][fn][r];
            }
        }
}

// ---------------------------------------------------------------------------
// GAT aggregation, half-wave/2-edge layout.
// Wave per node. lane = 32*el + l; el = edge-of-pair, l = channel-lane,
// channels [8l, 8l+8). Heads: l 0..15 = head0, l 16..31 = head1.
// Per pair of edges: each half gathers one 1KB xl row (2x b128/lane),
// dot+lrelu on 8 ch, 4-step shfl reduce within 16 lanes, exp, fma into acc.
// Final: combine halves via shfl_xor(32).
// LAST: fuse h@Wout+bout (out written directly), else emit bf16 hi/lo h.
// ---------------------------------------------------------------------------
template <int LAST>
__global__ __launch_bounds__(256) void gat_agg2(
        const float* __restrict__ xl, const float* __restrict__ xr,
        const float* __restrict__ att, const float* __restrict__ bias,
        const int* __restrict__ offsets, const int* __restrict__ csr_src,
        ushort* __restrict__ hhi, ushort* __restrict__ hlo,
        const float* __restrict__ Wout, const float* __restrict__ bout,
        float* __restrict__ out, int nNodes) {
    int wid  = threadIdx.x >> 6;
    int lane = threadIdx.x & 63;
    int node = blockIdx.x * 4 + wid;
    if (node >= nNodes) return;
    int el = lane >> 5;          // 0/1: which edge of the pair
    int l  = lane & 31;          // channel-lane
    int c0 = l * 8;

    float att8[8], xr8[8];
    *(float4*)&att8[0] = *(const float4*)&att[c0];
    *(float4*)&att8[4] = *(const float4*)&att[c0 + 4];
    *(float4*)&xr8[0]  = *(const float4*)&xr[(size_t)node * NCH + c0];
    *(float4*)&xr8[4]  = *(const float4*)&xr[(size_t)node * NCH + c0 + 4];

    int begin = offsets[node], end = offsets[node + 1];
    float denom = 0.f;
    float acc8[8];
    #pragma unroll
    for (int c = 0; c < 8; ++c) acc8[c] = 0.f;

    for (int base = begin; base < end; base += 64) {
        int rem = end - base;
        int cnt = rem < 64 ? rem : 64;
        int sv  = (lane < rem) ? csr_src[base + lane] : 0;

        auto body = [&](int idx) {
            bool val = idx < cnt;
            int s = __shfl(sv, val ? idx : 0, 64);
            const float* row = xl + (size_t)s * NCH + c0;
            float x8[8];
            *(float4*)&x8[0] = *(const float4*)row;
            *(float4*)&x8[4] = *(const float4*)(row + 4);
            float p = 0.f;
            #pragma unroll
            for (int c = 0; c < 8; ++c) {
                float tsum = x8[c] + xr8[c];
                float m = fmaf(LEAKY, fminf(tsum, 0.f), fmaxf(tsum, 0.f));
                p = fmaf(m, att8[c], p);
            }
            p += __shfl_xor(p, 1);
            p += __shfl_xor(p, 2);
            p += __shfl_xor(p, 4);
            p += __shfl_xor(p, 8);
            float ex = val ? __expf(p) : 0.f;
            denom += ex;
            #pragma unroll
            for (int c = 0; c < 8; ++c) acc8[c] = fmaf(ex, x8[c], acc8[c]);
        };

        for (int j = 0; j < cnt; j += 4) {
            body(j + el);
            if (j + 2 < cnt) body(j + 2 + el);
        }
    }

    // combine edge-halves
    #pragma unroll
    for (int c = 0; c < 8; ++c) acc8[c] += __shfl_xor(acc8[c], 32);
    denom += __shfl_xor(denom, 32);
    float rd = 1.0f / denom;

    float o8[8];
    float b8[8];
    *(float4*)&b8[0] = *(const float4*)&bias[c0];
    *(float4*)&b8[4] = *(const float4*)&bias[c0 + 4];
    #pragma unroll
    for (int c = 0; c < 8; ++c) o8[c] = fmaxf(fmaf(acc8[c], rd, b8[c]), 0.f);

    if (!LAST) {
        ushort h8[8], lo8[8];
        #pragma unroll
        for (int c = 0; c < 8; ++c) {
            h8[c]  = f2bf(o8[c]);
            lo8[c] = f2bf(o8[c] - bf2f(h8[c]));
        }
        *(uint4*)&hhi[(size_t)node * NCH + c0] = *(uint4*)&h8[0];
        *(uint4*)&hlo[(size_t)node * NCH + c0] = *(uint4*)&lo8[0];
    } else {
        float p0 = 0.f, p1 = 0.f, p2 = 0.f, p3 = 0.f;
        #pragma unroll
        for (int c = 0; c < 8; ++c) {
            float4 w4 = *(const float4*)&Wout[(size_t)(c0 + c) * 4];
            p0 = fmaf(o8[c], w4.x, p0);
            p1 = fmaf(o8[c], w4.y, p1);
            p2 = fmaf(o8[c], w4.z, p2);
            p3 = fmaf(o8[c], w4.w, p3);
        }
        #pragma unroll
        for (int off = 1; off < 32; off <<= 1) {
            p0 += __shfl_xor(p0, off);
            p1 += __shfl_xor(p1, off);
            p2 += __shfl_xor(p2, off);
            p3 += __shfl_xor(p3, off);
        }
        if (lane == 0) {
            float4 r;
            r.x = p0 + bout[0]; r.y = p1 + bout[1];
            r.z = p2 + bout[2]; r.w = p3 + bout[3];
            *(float4*)&out[(size_t)node * 4] = r;
        }
    }
}

// ---------------------------------------------------------------------------
extern "C" void kernel_launch(void* const* d_in, const int* in_sizes, int n_in,
                              void* d_out, int out_size, void* d_ws, size_t ws_size,
                              hipStream_t stream) {
    const float* x  = (const float*)d_in[0];
    const int*   ei = (const int*)d_in[1];
    const float* Wl[3]  = {(const float*)d_in[2], (const float*)d_in[6],  (const float*)d_in[10]};
    const float* Wr[3]  = {(const float*)d_in[3], (const float*)d_in[7],  (const float*)d_in[11]};
    const float* att[3] = {(const float*)d_in[4], (const float*)d_in[8],  (const float*)d_in[12]};
    const float* bb[3]  = {(const float*)d_in[5], (const float*)d_in[9],  (const float*)d_in[13]};
    const float* Wout = (const float*)d_in[14];
    const float* bout = (const float*)d_in[15];

    int Nn   = in_sizes[0] / NCH;       // 20000
    int E    = in_sizes[1] / 2;         // 320000
    int Etot = E + Nn;

    size_t NEf = (size_t)Nn * NCH;
    float*  xl   = (float*)d_ws;
    float*  xr   = xl + NEf;
    ushort* pAhi = (ushort*)(xr + NEf);
    ushort* pAlo = pAhi + NEf;
    ushort* pBhi = pAlo + NEf;
    ushort* pBlo = pBhi + NEf;
    ushort* wthi = pBlo + NEf;                 // 6 * 65536
    ushort* wtlo = wthi + 6 * 65536;
    int*   counts  = (int*)(wtlo + 6 * 65536);
    int*   offsets = counts + Nn;
    int*   cursor  = offsets + (Nn + 1);
    int*   csr_src = cursor + Nn;

    hipMemsetAsync(counts, 0, (size_t)Nn * sizeof(int), stream);
    int eblocks = (Etot + 255) / 256;
    count_kernel<<<eblocks, 256, 0, stream>>>(ei, E, Nn, counts);
    scan_kernel<<<1, 1024, 0, stream>>>(counts, offsets, cursor, Nn);
    scatter_kernel<<<eblocks, 256, 0, stream>>>(ei, E, Nn, cursor, csr_src);

    WPtrs wp = {{Wl[0], Wr[0], Wl[1], Wr[1], Wl[2], Wr[2]}};
    wsplit_kernel<<<dim3(8, 8, 6), dim3(32, 32), 0, stream>>>(wp, wthi, wtlo);

    int n4 = (int)(NEf / 4);
    split_kernel<<<(n4 + 255) / 256, 256, 0, stream>>>(x, pAhi, pAlo, n4);

    dim3 ggrid((Nn + 127) / 128, 4);
    int  ngrid = (Nn + 3) / 4;

    ushort* curHi = pAhi; ushort* curLo = pAlo;
    ushort* nxtHi = pBhi; ushort* nxtLo = pBlo;
    for (int l = 0; l < 3; ++l) {
        dual_gemm_mfma<<<ggrid, 256, 0, stream>>>(
            curHi, curLo, wthi + (size_t)l * 2 * 65536, wtlo + (size_t)l * 2 * 65536,
            xl, xr, Nn);
        if (l < 2) {
            gat_agg2<0><<<ngrid, 256, 0, stream>>>(xl, xr, att[l], bb[l],
                offsets, csr_src, nxtHi, nxtLo, nullptr, nullptr, nullptr, Nn);
        } else {
            gat_agg2<1><<<ngrid, 256, 0, stream>>>(xl, xr, att[l], bb[l],
                offsets, csr_src, nullptr, nullptr, Wout, bout, (float*)d_out, Nn);
        }
        ushort* th = curHi; ushort* tl = curLo;
        curHi = nxtHi; curLo = nxtLo; nxtHi = th; nxtLo = tl;
    }
}

// Round 5
// 283.340 us; speedup vs baseline: 2.1441x; 1.0771x over previous
//
#include <hip/hip_runtime.h>
#include <hip/hip_bf16.h>
#include <hip/hip_fp16.h>
#include <math.h>

// N=20000, E=320000, layers: [N,256]@[256,256] GEMMs, HEADS=2, HID=128.
#define NCH 256
#define LEAKY 0.2f

typedef __attribute__((ext_vector_type(8))) short bf16x8;  // 4 VGPRs
typedef __attribute__((ext_vector_type(4))) float f32x4;   // MFMA C/D

static __device__ __forceinline__ ushort f2bf(float f) {
    unsigned u = __float_as_uint(f);
    u += 0x7fffu + ((u >> 16) & 1u);          // RNE
    return (ushort)(u >> 16);
}
static __device__ __forceinline__ float bf2f(ushort h) {
    return __uint_as_float(((unsigned)h) << 16);
}

// ---------------------------------------------------------------------------
// CSR build: counts -> scan -> scatter
// ---------------------------------------------------------------------------
__global__ void count_kernel(const int* __restrict__ ei, int E, int n,
                             int* __restrict__ counts) {
    int tid = blockIdx.x * 256 + threadIdx.x;
    int tot = E + n;
    if (tid >= tot) return;
    int dst = (tid < E) ? ei[E + tid] : (tid - E);
    atomicAdd(&counts[dst], 1);
}

__global__ void scan_kernel(const int* __restrict__ counts,
                            int* __restrict__ offsets,
                            int* __restrict__ cursor, int n) {
    __shared__ int wsum[16];
    int tid  = threadIdx.x;          // 1024 threads = 16 waves
    int lane = tid & 63, w = tid >> 6;
    int carry = 0;
    for (int base = 0; base < n; base += 1024) {
        int idx = base + tid;
        int v = (idx < n) ? counts[idx] : 0;
        int incl = v;
        #pragma unroll
        for (int off = 1; off < 64; off <<= 1) {
            int t2 = __shfl_up(incl, off, 64);
            if (lane >= off) incl += t2;
        }
        if (lane == 63) wsum[w] = incl;
        __syncthreads();
        if (w == 0 && lane < 16) {
            int s = wsum[lane];
            #pragma unroll
            for (int off = 1; off < 16; off <<= 1) {
                int t2 = __shfl_up(s, off, 64);
                if (lane >= off) s += t2;
            }
            wsum[lane] = s;
        }
        __syncthreads();
        int wpre = (w == 0) ? 0 : wsum[w - 1];
        int excl = carry + wpre + incl - v;
        if (idx < n) { offsets[idx] = excl; cursor[idx] = excl; }
        carry += wsum[15];
        __syncthreads();
    }
    if (tid == 0) offsets[n] = carry;
}

__global__ void scatter_kernel(const int* __restrict__ ei, int E, int n,
                               int* __restrict__ cursor,
                               int* __restrict__ csr_src) {
    int tid = blockIdx.x * 256 + threadIdx.x;
    int tot = E + n;
    if (tid >= tot) return;
    int src, dst;
    if (tid < E) { src = ei[tid]; dst = ei[E + tid]; }
    else         { src = dst = tid - E; }
    int pos = atomicAdd(&cursor[dst], 1);
    csr_src[pos] = src;
}

// ---------------------------------------------------------------------------
// fp32 -> bf16 hi/lo split (layer-1 input x only)
// ---------------------------------------------------------------------------
__global__ void split_kernel(const float* __restrict__ in,
                             ushort* __restrict__ hi, ushort* __restrict__ lo,
                             int n4) {
    int i = blockIdx.x * 256 + threadIdx.x;
    if (i >= n4) return;
    float4 v = ((const float4*)in)[i];
    ushort h0 = f2bf(v.x), h1 = f2bf(v.y), h2 = f2bf(v.z), h3 = f2bf(v.w);
    ((ushort4*)hi)[i] = make_ushort4(h0, h1, h2, h3);
    ((ushort4*)lo)[i] = make_ushort4(f2bf(v.x - bf2f(h0)), f2bf(v.y - bf2f(h1)),
                                     f2bf(v.z - bf2f(h2)), f2bf(v.w - bf2f(h3)));
}

// ---------------------------------------------------------------------------
// Weight transpose+split: W[256,256] -> Wt[256,256] (n-major) bf16 hi/lo.
// ---------------------------------------------------------------------------
struct WPtrs { const float* w[6]; };
__global__ __launch_bounds__(1024) void wsplit_kernel(WPtrs p,
        ushort* __restrict__ hi, ushort* __restrict__ lo) {
    __shared__ float tile[32][33];
    int m = blockIdx.z;
    const float* W = p.w[m];
    size_t base = (size_t)m * 65536;
    int k = blockIdx.y * 32 + threadIdx.y;
    int n = blockIdx.x * 32 + threadIdx.x;
    tile[threadIdx.y][threadIdx.x] = W[k * NCH + n];
    __syncthreads();
    int on = blockIdx.x * 32 + threadIdx.y;
    int ok = blockIdx.y * 32 + threadIdx.x;
    float v = tile[threadIdx.x][threadIdx.y];
    ushort h = f2bf(v);
    hi[base + (size_t)on * NCH + ok] = h;
    lo[base + (size_t)on * NCH + ok] = f2bf(v - bf2f(h));
}

// ---------------------------------------------------------------------------
// MFMA dual GEMM with bf16 hi/lo split (3-product fp32-accurate).
// xl is written as fp16 (gather side: halves L2-miss traffic); xr as fp32.
// ---------------------------------------------------------------------------
#define LDK 40
__global__ __launch_bounds__(256) void dual_gemm_mfma(
        const ushort* __restrict__ Ahi, const ushort* __restrict__ Alo,
        const ushort* __restrict__ Bthi, const ushort* __restrict__ Btlo,
        __half* __restrict__ xlh, float* __restrict__ xr, int M) {
    __shared__ ushort As[2][128 * LDK];
    __shared__ ushort Bs[2][128 * LDK];
    int cb = blockIdx.y;
    const ushort* Bh = Bthi + (size_t)(cb >> 1) * 65536;
    const ushort* Bl = Btlo + (size_t)(cb >> 1) * 65536;
    int col0 = (cb & 1) * 128;
    int row0 = blockIdx.x * 128;
    int t = threadIdx.x;
    int lane = t & 63, w = t >> 6;
    int wr = w >> 1, wc = w & 1;
    int l15 = lane & 15, l4 = lane >> 4;

    f32x4 acc[4][4];
    #pragma unroll
    for (int i = 0; i < 4; ++i)
        #pragma unroll
        for (int j = 0; j < 4; ++j) acc[i][j] = (f32x4){0.f, 0.f, 0.f, 0.f};

    int r0 = t >> 2,          q0 = (t & 3) * 8;
    int r1 = (t + 256) >> 2,  q1 = ((t + 256) & 3) * 8;

    for (int k0 = 0; k0 < 256; k0 += 32) {
        uint4 z = make_uint4(0, 0, 0, 0);
        uint4 a0h = z, a0l = z, a1h = z, a1l = z;
        if (row0 + r0 < M) {
            a0h = *(const uint4*)&Ahi[(size_t)(row0 + r0) * NCH + k0 + q0];
            a0l = *(const uint4*)&Alo[(size_t)(row0 + r0) * NCH + k0 + q0];
        }
        if (row0 + r1 < M) {
            a1h = *(const uint4*)&Ahi[(size_t)(row0 + r1) * NCH + k0 + q1];
            a1l = *(const uint4*)&Alo[(size_t)(row0 + r1) * NCH + k0 + q1];
        }
        uint4 b0h = *(const uint4*)&Bh[(size_t)(col0 + r0) * NCH + k0 + q0];
        uint4 b0l = *(const uint4*)&Bl[(size_t)(col0 + r0) * NCH + k0 + q0];
        uint4 b1h = *(const uint4*)&Bh[(size_t)(col0 + r1) * NCH + k0 + q1];
        uint4 b1l = *(const uint4*)&Bl[(size_t)(col0 + r1) * NCH + k0 + q1];
        __syncthreads();
        *(uint4*)&As[0][r0 * LDK + q0] = a0h;
        *(uint4*)&As[1][r0 * LDK + q0] = a0l;
        *(uint4*)&As[0][r1 * LDK + q1] = a1h;
        *(uint4*)&As[1][r1 * LDK + q1] = a1l;
        *(uint4*)&Bs[0][r0 * LDK + q0] = b0h;
        *(uint4*)&Bs[1][r0 * LDK + q0] = b0l;
        *(uint4*)&Bs[0][r1 * LDK + q1] = b1h;
        *(uint4*)&Bs[1][r1 * LDK + q1] = b1l;
        __syncthreads();

        bf16x8 af[4][2], bq[4][2];
        #pragma unroll
        for (int fm = 0; fm < 4; ++fm) {
            int addr = (wr * 64 + fm * 16 + l15) * LDK + l4 * 8;
            af[fm][0] = *(const bf16x8*)&As[0][addr];
            af[fm][1] = *(const bf16x8*)&As[1][addr];
        }
        #pragma unroll
        for (int fn = 0; fn < 4; ++fn) {
            int addr = (wc * 64 + fn * 16 + l15) * LDK + l4 * 8;
            bq[fn][0] = *(const bf16x8*)&Bs[0][addr];
            bq[fn][1] = *(const bf16x8*)&Bs[1][addr];
        }
        #pragma unroll
        for (int fm = 0; fm < 4; ++fm)
            #pragma unroll
            for (int fn = 0; fn < 4; ++fn) {
                acc[fm][fn] = __builtin_amdgcn_mfma_f32_16x16x32_bf16(
                    af[fm][0], bq[fn][0], acc[fm][fn], 0, 0, 0);
                acc[fm][fn] = __builtin_amdgcn_mfma_f32_16x16x32_bf16(
                    af[fm][0], bq[fn][1], acc[fm][fn], 0, 0, 0);
                acc[fm][fn] = __builtin_amdgcn_mfma_f32_16x16x32_bf16(
                    af[fm][1], bq[fn][0], acc[fm][fn], 0, 0, 0);
            }
    }

    #pragma unroll
    for (int fm = 0; fm < 4; ++fm)
        #pragma unroll
        for (int fn = 0; fn < 4; ++fn) {
            int col = col0 + wc * 64 + fn * 16 + l15;
            #pragma unroll
            for (int r = 0; r < 4; ++r) {
                int row = row0 + wr * 64 + fm * 16 + l4 * 4 + r;
                if (row < M) {
                    if (cb < 2)
                        xlh[(size_t)row * NCH + col] = __float2half_rn(acc[fm][fn][r]);
                    else
                        xr[(size_t)row * NCH + col] = acc[fm][fn][r];
                }
            }
        }
}

// ---------------------------------------------------------------------------
// GAT aggregation: wave per node, 4 ch/lane, fp16 xl gathers (512B rows),
// scalarized index stream (readfirstlane node -> s_load offsets/csr_src),
// flat groups of 8 edges (clamped dummies hit L1, no extra TCC traffic).
// ---------------------------------------------------------------------------
template <int LAST>
__global__ __launch_bounds__(256) void gat_agg3(
        const __half* __restrict__ xlh, const float* __restrict__ xr,
        const float* __restrict__ att, const float* __restrict__ bias,
        const int* __restrict__ offsets, const int* __restrict__ csr_src,
        ushort* __restrict__ hhi, ushort* __restrict__ hlo,
        const float* __restrict__ Wout, const float* __restrict__ bout,
        float* __restrict__ out, int nNodes) {
    int wid  = threadIdx.x >> 6;
    int lane = threadIdx.x & 63;
    int node = blockIdx.x * 4 + wid;
    if (node >= nNodes) return;
    node = __builtin_amdgcn_readfirstlane(node);   // wave-uniform -> SGPR
    int c0 = lane * 4;

    float4 att4 = *(const float4*)&att[c0];
    float4 xr4  = *(const float4*)&xr[(size_t)node * NCH + c0];
    int begin = offsets[node], end = offsets[node + 1];

    float denom = 0.f;
    float4 acc = make_float4(0.f, 0.f, 0.f, 0.f);

    for (int j = begin; j < end; j += 8) {
        int idx[8];
        uint2 rv[8];
        float p[8];
        #pragma unroll
        for (int k = 0; k < 8; ++k) {
            int jj = j + k;
            if (jj >= end) jj = end - 1;           // scalar clamp
            idx[k] = csr_src[jj];                  // uniform -> s_load
        }
        #pragma unroll
        for (int k = 0; k < 8; ++k)
            rv[k] = *(const uint2*)&xlh[(size_t)idx[k] * NCH + c0];
        #pragma unroll
        for (int k = 0; k < 8; ++k) {
            float2 f01 = __half22float2(*(const __half2*)&rv[k].x);
            float2 f23 = __half22float2(*(const __half2*)&rv[k].y);
            float tv, pk = 0.f;
            tv = f01.x + xr4.x; tv = fmaf(LEAKY, fminf(tv, 0.f), fmaxf(tv, 0.f));
            pk = fmaf(tv, att4.x, pk);
            tv = f01.y + xr4.y; tv = fmaf(LEAKY, fminf(tv, 0.f), fmaxf(tv, 0.f));
            pk = fmaf(tv, att4.y, pk);
            tv = f23.x + xr4.z; tv = fmaf(LEAKY, fminf(tv, 0.f), fmaxf(tv, 0.f));
            pk = fmaf(tv, att4.z, pk);
            tv = f23.y + xr4.w; tv = fmaf(LEAKY, fminf(tv, 0.f), fmaxf(tv, 0.f));
            pk = fmaf(tv, att4.w, pk);
            p[k] = pk;
        }
        #pragma unroll
        for (int off = 16; off > 0; off >>= 1)
            #pragma unroll
            for (int k = 0; k < 8; ++k) p[k] += __shfl_xor(p[k], off, 32);
        #pragma unroll
        for (int k = 0; k < 8; ++k) {
            float ex = (j + k < end) ? __expf(p[k]) : 0.f;
            denom += ex;
            float2 f01 = __half22float2(*(const __half2*)&rv[k].x);
            float2 f23 = __half22float2(*(const __half2*)&rv[k].y);
            acc.x = fmaf(ex, f01.x, acc.x);
            acc.y = fmaf(ex, f01.y, acc.y);
            acc.z = fmaf(ex, f23.x, acc.z);
            acc.w = fmaf(ex, f23.y, acc.w);
        }
    }

    float rd = 1.0f / denom;
    float4 b4 = *(const float4*)&bias[c0];
    float o0 = fmaxf(fmaf(acc.x, rd, b4.x), 0.f);
    float o1 = fmaxf(fmaf(acc.y, rd, b4.y), 0.f);
    float o2 = fmaxf(fmaf(acc.z, rd, b4.z), 0.f);
    float o3 = fmaxf(fmaf(acc.w, rd, b4.w), 0.f);

    if (!LAST) {
        ushort h0 = f2bf(o0), h1 = f2bf(o1), h2 = f2bf(o2), h3 = f2bf(o3);
        *(ushort4*)&hhi[(size_t)node * NCH + c0] = make_ushort4(h0, h1, h2, h3);
        *(ushort4*)&hlo[(size_t)node * NCH + c0] =
            make_ushort4(f2bf(o0 - bf2f(h0)), f2bf(o1 - bf2f(h1)),
                         f2bf(o2 - bf2f(h2)), f2bf(o3 - bf2f(h3)));
    } else {
        float p0 = 0.f, p1 = 0.f, p2 = 0.f, p3 = 0.f;
        float ov[4] = {o0, o1, o2, o3};
        #pragma unroll
        for (int c = 0; c < 4; ++c) {
            float4 w4 = *(const float4*)&Wout[(size_t)(c0 + c) * 4];
            p0 = fmaf(ov[c], w4.x, p0);
            p1 = fmaf(ov[c], w4.y, p1);
            p2 = fmaf(ov[c], w4.z, p2);
            p3 = fmaf(ov[c], w4.w, p3);
        }
        #pragma unroll
        for (int off = 1; off < 64; off <<= 1) {
            p0 += __shfl_xor(p0, off);
            p1 += __shfl_xor(p1, off);
            p2 += __shfl_xor(p2, off);
            p3 += __shfl_xor(p3, off);
        }
        if (lane == 0) {
            float4 r;
            r.x = p0 + bout[0]; r.y = p1 + bout[1];
            r.z = p2 + bout[2]; r.w = p3 + bout[3];
            *(float4*)&out[(size_t)node * 4] = r;
        }
    }
}

// ---------------------------------------------------------------------------
extern "C" void kernel_launch(void* const* d_in, const int* in_sizes, int n_in,
                              void* d_out, int out_size, void* d_ws, size_t ws_size,
                              hipStream_t stream) {
    const float* x  = (const float*)d_in[0];
    const int*   ei = (const int*)d_in[1];
    const float* Wl[3]  = {(const float*)d_in[2], (const float*)d_in[6],  (const float*)d_in[10]};
    const float* Wr[3]  = {(const float*)d_in[3], (const float*)d_in[7],  (const float*)d_in[11]};
    const float* att[3] = {(const float*)d_in[4], (const float*)d_in[8],  (const float*)d_in[12]};
    const float* bb[3]  = {(const float*)d_in[5], (const float*)d_in[9],  (const float*)d_in[13]};
    const float* Wout = (const float*)d_in[14];
    const float* bout = (const float*)d_in[15];

    int Nn   = in_sizes[0] / NCH;       // 20000
    int E    = in_sizes[1] / 2;         // 320000
    int Etot = E + Nn;

    size_t NEf = (size_t)Nn * NCH;
    __half* xlh  = (__half*)d_ws;                  // NEf halves
    float*  xr   = (float*)(xlh + NEf);
    ushort* pAhi = (ushort*)(xr + NEf);
    ushort* pAlo = pAhi + NEf;
    ushort* pBhi = pAlo + NEf;
    ushort* pBlo = pBhi + NEf;
    ushort* wthi = pBlo + NEf;                     // 6 * 65536
    ushort* wtlo = wthi + 6 * 65536;
    int*   counts  = (int*)(wtlo + 6 * 65536);
    int*   offsets = counts + Nn;
    int*   cursor  = offsets + (Nn + 1);
    int*   csr_src = cursor + Nn;

    hipMemsetAsync(counts, 0, (size_t)Nn * sizeof(int), stream);
    int eblocks = (Etot + 255) / 256;
    count_kernel<<<eblocks, 256, 0, stream>>>(ei, E, Nn, counts);
    scan_kernel<<<1, 1024, 0, stream>>>(counts, offsets, cursor, Nn);
    scatter_kernel<<<eblocks, 256, 0, stream>>>(ei, E, Nn, cursor, csr_src);

    WPtrs wp = {{Wl[0], Wr[0], Wl[1], Wr[1], Wl[2], Wr[2]}};
    wsplit_kernel<<<dim3(8, 8, 6), dim3(32, 32), 0, stream>>>(wp, wthi, wtlo);

    int n4 = (int)(NEf / 4);
    split_kernel<<<(n4 + 255) / 256, 256, 0, stream>>>(x, pAhi, pAlo, n4);

    dim3 ggrid((Nn + 127) / 128, 4);
    int  ngrid = (Nn + 3) / 4;

    ushort* curHi = pAhi; ushort* curLo = pAlo;
    ushort* nxtHi = pBhi; ushort* nxtLo = pBlo;
    for (int l = 0; l < 3; ++l) {
        dual_gemm_mfma<<<ggrid, 256, 0, stream>>>(
            curHi, curLo, wthi + (size_t)l * 2 * 65536, wtlo + (size_t)l * 2 * 65536,
            xlh, xr, Nn);
        if (l < 2) {
            gat_agg3<0><<<ngrid, 256, 0, stream>>>(xlh, xr, att[l], bb[l],
                offsets, csr_src, nxtHi, nxtLo, nullptr, nullptr, nullptr, Nn);
        } else {
            gat_agg3<1><<<ngrid, 256, 0, stream>>>(xlh, xr, att[l], bb[l],
                offsets, csr_src, nullptr, nullptr, Wout, bout, (float*)d_out, Nn);
        }
        ushort* th = curHi; ushort* tl = curLo;
        curHi = nxtHi; curLo = nxtLo; nxtHi = th; nxtLo = tl;
    }
}

// Round 6
// 279.310 us; speedup vs baseline: 2.1751x; 1.0144x over previous
//
#include <hip/hip_runtime.h>
#include <hip/hip_bf16.h>
#include <hip/hip_fp16.h>
#include <math.h>

// N=20000, E=320000, layers: [N,256]@[256,256] GEMMs, HEADS=2, HID=128.
#define NCH 256
#define LEAKY 0.2f

typedef __attribute__((ext_vector_type(8))) short bf16x8;  // 4 VGPRs
typedef __attribute__((ext_vector_type(4))) float f32x4;   // MFMA C/D

static __device__ __forceinline__ ushort f2bf(float f) {
    unsigned u = __float_as_uint(f);
    u += 0x7fffu + ((u >> 16) & 1u);          // RNE
    return (ushort)(u >> 16);
}
static __device__ __forceinline__ float bf2f(ushort h) {
    return __uint_as_float(((unsigned)h) << 16);
}

// ---------------------------------------------------------------------------
// CSR build: counts -> scan -> scatter
// ---------------------------------------------------------------------------
__global__ void count_kernel(const int* __restrict__ ei, int E, int n,
                             int* __restrict__ counts) {
    int tid = blockIdx.x * 256 + threadIdx.x;
    int tot = E + n;
    if (tid >= tot) return;
    int dst = (tid < E) ? ei[E + tid] : (tid - E);
    atomicAdd(&counts[dst], 1);
}

__global__ void scan_kernel(const int* __restrict__ counts,
                            int* __restrict__ offsets,
                            int* __restrict__ cursor, int n) {
    __shared__ int wsum[16];
    int tid  = threadIdx.x;          // 1024 threads = 16 waves
    int lane = tid & 63, w = tid >> 6;
    int carry = 0;
    for (int base = 0; base < n; base += 1024) {
        int idx = base + tid;
        int v = (idx < n) ? counts[idx] : 0;
        int incl = v;
        #pragma unroll
        for (int off = 1; off < 64; off <<= 1) {
            int t2 = __shfl_up(incl, off, 64);
            if (lane >= off) incl += t2;
        }
        if (lane == 63) wsum[w] = incl;
        __syncthreads();
        if (w == 0 && lane < 16) {
            int s = wsum[lane];
            #pragma unroll
            for (int off = 1; off < 16; off <<= 1) {
                int t2 = __shfl_up(s, off, 64);
                if (lane >= off) s += t2;
            }
            wsum[lane] = s;
        }
        __syncthreads();
        int wpre = (w == 0) ? 0 : wsum[w - 1];
        int excl = carry + wpre + incl - v;
        if (idx < n) { offsets[idx] = excl; cursor[idx] = excl; }
        carry += wsum[15];
        __syncthreads();
    }
    if (tid == 0) offsets[n] = carry;
}

__global__ void scatter_kernel(const int* __restrict__ ei, int E, int n,
                               int* __restrict__ cursor,
                               int* __restrict__ csr_src) {
    int tid = blockIdx.x * 256 + threadIdx.x;
    int tot = E + n;
    if (tid >= tot) return;
    int src, dst;
    if (tid < E) { src = ei[tid]; dst = ei[E + tid]; }
    else         { src = dst = tid - E; }
    int pos = atomicAdd(&cursor[dst], 1);
    csr_src[pos] = src;
}

// ---------------------------------------------------------------------------
// fp32 -> bf16 hi/lo split (layer-1 input x only)
// ---------------------------------------------------------------------------
__global__ void split_kernel(const float* __restrict__ in,
                             ushort* __restrict__ hi, ushort* __restrict__ lo,
                             int n4) {
    int i = blockIdx.x * 256 + threadIdx.x;
    if (i >= n4) return;
    float4 v = ((const float4*)in)[i];
    ushort h0 = f2bf(v.x), h1 = f2bf(v.y), h2 = f2bf(v.z), h3 = f2bf(v.w);
    ((ushort4*)hi)[i] = make_ushort4(h0, h1, h2, h3);
    ((ushort4*)lo)[i] = make_ushort4(f2bf(v.x - bf2f(h0)), f2bf(v.y - bf2f(h1)),
                                     f2bf(v.z - bf2f(h2)), f2bf(v.w - bf2f(h3)));
}

// ---------------------------------------------------------------------------
// Weight transpose+split: W[256,256] -> Wt[256,256] (n-major) bf16 hi/lo.
// ---------------------------------------------------------------------------
struct WPtrs { const float* w[6]; };
__global__ __launch_bounds__(1024) void wsplit_kernel(WPtrs p,
        ushort* __restrict__ hi, ushort* __restrict__ lo) {
    __shared__ float tile[32][33];
    int m = blockIdx.z;
    const float* W = p.w[m];
    size_t base = (size_t)m * 65536;
    int k = blockIdx.y * 32 + threadIdx.y;
    int n = blockIdx.x * 32 + threadIdx.x;
    tile[threadIdx.y][threadIdx.x] = W[k * NCH + n];
    __syncthreads();
    int on = blockIdx.x * 32 + threadIdx.y;
    int ok = blockIdx.y * 32 + threadIdx.x;
    float v = tile[threadIdx.x][threadIdx.y];
    ushort h = f2bf(v);
    hi[base + (size_t)on * NCH + ok] = h;
    lo[base + (size_t)on * NCH + ok] = f2bf(v - bf2f(h));
}

// ---------------------------------------------------------------------------
// MFMA dual GEMM with bf16 hi/lo split (3-product fp32-accurate).
// xl is written as fp16 (gather side: halves L2-miss traffic); xr as fp32.
// ---------------------------------------------------------------------------
#define LDK 40
__global__ __launch_bounds__(256) void dual_gemm_mfma(
        const ushort* __restrict__ Ahi, const ushort* __restrict__ Alo,
        const ushort* __restrict__ Bthi, const ushort* __restrict__ Btlo,
        __half* __restrict__ xlh, float* __restrict__ xr, int M) {
    __shared__ ushort As[2][128 * LDK];
    __shared__ ushort Bs[2][128 * LDK];
    int cb = blockIdx.y;
    const ushort* Bh = Bthi + (size_t)(cb >> 1) * 65536;
    const ushort* Bl = Btlo + (size_t)(cb >> 1) * 65536;
    int col0 = (cb & 1) * 128;
    int row0 = blockIdx.x * 128;
    int t = threadIdx.x;
    int lane = t & 63, w = t >> 6;
    int wr = w >> 1, wc = w & 1;
    int l15 = lane & 15, l4 = lane >> 4;

    f32x4 acc[4][4];
    #pragma unroll
    for (int i = 0; i < 4; ++i)
        #pragma unroll
        for (int j = 0; j < 4; ++j) acc[i][j] = (f32x4){0.f, 0.f, 0.f, 0.f};

    int r0 = t >> 2,          q0 = (t & 3) * 8;
    int r1 = (t + 256) >> 2,  q1 = ((t + 256) & 3) * 8;

    for (int k0 = 0; k0 < 256; k0 += 32) {
        uint4 z = make_uint4(0, 0, 0, 0);
        uint4 a0h = z, a0l = z, a1h = z, a1l = z;
        if (row0 + r0 < M) {
            a0h = *(const uint4*)&Ahi[(size_t)(row0 + r0) * NCH + k0 + q0];
            a0l = *(const uint4*)&Alo[(size_t)(row0 + r0) * NCH + k0 + q0];
        }
        if (row0 + r1 < M) {
            a1h = *(const uint4*)&Ahi[(size_t)(row0 + r1) * NCH + k0 + q1];
            a1l = *(const uint4*)&Alo[(size_t)(row0 + r1) * NCH + k0 + q1];
        }
        uint4 b0h = *(const uint4*)&Bh[(size_t)(col0 + r0) * NCH + k0 + q0];
        uint4 b0l = *(const uint4*)&Bl[(size_t)(col0 + r0) * NCH + k0 + q0];
        uint4 b1h = *(const uint4*)&Bh[(size_t)(col0 + r1) * NCH + k0 + q1];
        uint4 b1l = *(const uint4*)&Bl[(size_t)(col0 + r1) * NCH + k0 + q1];
        __syncthreads();
        *(uint4*)&As[0][r0 * LDK + q0] = a0h;
        *(uint4*)&As[1][r0 * LDK + q0] = a0l;
        *(uint4*)&As[0][r1 * LDK + q1] = a1h;
        *(uint4*)&As[1][r1 * LDK + q1] = a1l;
        *(uint4*)&Bs[0][r0 * LDK + q0] = b0h;
        *(uint4*)&Bs[1][r0 * LDK + q0] = b0l;
        *(uint4*)&Bs[0][r1 * LDK + q1] = b1h;
        *(uint4*)&Bs[1][r1 * LDK + q1] = b1l;
        __syncthreads();

        bf16x8 af[4][2], bq[4][2];
        #pragma unroll
        for (int fm = 0; fm < 4; ++fm) {
            int addr = (wr * 64 + fm * 16 + l15) * LDK + l4 * 8;
            af[fm][0] = *(const bf16x8*)&As[0][addr];
            af[fm][1] = *(const bf16x8*)&As[1][addr];
        }
        #pragma unroll
        for (int fn = 0; fn < 4; ++fn) {
            int addr = (wc * 64 + fn * 16 + l15) * LDK + l4 * 8;
            bq[fn][0] = *(const bf16x8*)&Bs[0][addr];
            bq[fn][1] = *(const bf16x8*)&Bs[1][addr];
        }
        #pragma unroll
        for (int fm = 0; fm < 4; ++fm)
            #pragma unroll
            for (int fn = 0; fn < 4; ++fn) {
                acc[fm][fn] = __builtin_amdgcn_mfma_f32_16x16x32_bf16(
                    af[fm][0], bq[fn][0], acc[fm][fn], 0, 0, 0);
                acc[fm][fn] = __builtin_amdgcn_mfma_f32_16x16x32_bf16(
                    af[fm][0], bq[fn][1], acc[fm][fn], 0, 0, 0);
                acc[fm][fn] = __builtin_amdgcn_mfma_f32_16x16x32_bf16(
                    af[fm][1], bq[fn][0], acc[fm][fn], 0, 0, 0);
            }
    }

    #pragma unroll
    for (int fm = 0; fm < 4; ++fm)
        #pragma unroll
        for (int fn = 0; fn < 4; ++fn) {
            int col = col0 + wc * 64 + fn * 16 + l15;
            #pragma unroll
            for (int r = 0; r < 4; ++r) {
                int row = row0 + wr * 64 + fm * 16 + l4 * 4 + r;
                if (row < M) {
                    if (cb < 2)
                        xlh[(size_t)row * NCH + col] = __float2half_rn(acc[fm][fn][r]);
                    else
                        xr[(size_t)row * NCH + col] = acc[fm][fn][r];
                }
            }
        }
}

// ---------------------------------------------------------------------------
// GAT aggregation v4: persistent grid-stride waves, half-wave pair layout.
// lane = 32*el + l; el = edge-of-pair, l = channel-lane, channels [8l,8l+8).
// Heads: l 0..15 = head0, l 16..31 = head1 (reduce within 16-lane groups).
// One uint4 (16B fp16) load fetches 2 edge-rows per instruction; 2 pairs
// (4 edges) in flight per iteration.
// ---------------------------------------------------------------------------
template <int LAST>
__global__ __launch_bounds__(256) void gat_agg4(
        const __half* __restrict__ xlh, const float* __restrict__ xr,
        const float* __restrict__ att, const float* __restrict__ bias,
        const int* __restrict__ offsets, const int* __restrict__ csr_src,
        ushort* __restrict__ hhi, ushort* __restrict__ hlo,
        const float* __restrict__ Wout, const float* __restrict__ bout,
        float* __restrict__ out, int nNodes) {
    int wid  = threadIdx.x >> 6;
    int lane = threadIdx.x & 63;
    int el = lane >> 5;
    int l  = lane & 31;
    int c0 = l * 8;

    float att8[8];
    *(float4*)&att8[0] = *(const float4*)&att[c0];
    *(float4*)&att8[4] = *(const float4*)&att[c0 + 4];

    int stride = gridDim.x << 2;
    for (int node0 = (blockIdx.x << 2) + wid; node0 < nNodes; node0 += stride) {
        int node = __builtin_amdgcn_readfirstlane(node0);
        float xr8[8];
        *(float4*)&xr8[0] = *(const float4*)&xr[(size_t)node * NCH + c0];
        *(float4*)&xr8[4] = *(const float4*)&xr[(size_t)node * NCH + c0 + 4];
        int begin = offsets[node], end = offsets[node + 1];

        float denom = 0.f;
        float acc8[8];
        #pragma unroll
        for (int c = 0; c < 8; ++c) acc8[c] = 0.f;

        for (int j = begin; j < end; j += 4) {
            int j1 = j + 1 < end ? j + 1 : end - 1;
            int j2 = j + 2 < end ? j + 2 : end - 1;
            int j3 = j + 3 < end ? j + 3 : end - 1;
            int i0 = csr_src[j];
            int i1 = csr_src[j1];
            int i2 = csr_src[j2];
            int i3 = csr_src[j3];
            int sA = el ? i1 : i0;
            int sB = el ? i3 : i2;
            uint4 rA = *(const uint4*)&xlh[(size_t)sA * NCH + c0];
            uint4 rB = *(const uint4*)&xlh[(size_t)sB * NCH + c0];

            float a8[8], b8[8];
            {
                float2 t0 = __half22float2(*(const __half2*)&rA.x);
                float2 t1 = __half22float2(*(const __half2*)&rA.y);
                float2 t2 = __half22float2(*(const __half2*)&rA.z);
                float2 t3 = __half22float2(*(const __half2*)&rA.w);
                a8[0] = t0.x; a8[1] = t0.y; a8[2] = t1.x; a8[3] = t1.y;
                a8[4] = t2.x; a8[5] = t2.y; a8[6] = t3.x; a8[7] = t3.y;
                t0 = __half22float2(*(const __half2*)&rB.x);
                t1 = __half22float2(*(const __half2*)&rB.y);
                t2 = __half22float2(*(const __half2*)&rB.z);
                t3 = __half22float2(*(const __half2*)&rB.w);
                b8[0] = t0.x; b8[1] = t0.y; b8[2] = t1.x; b8[3] = t1.y;
                b8[4] = t2.x; b8[5] = t2.y; b8[6] = t3.x; b8[7] = t3.y;
            }
            float pA = 0.f, pB = 0.f;
            #pragma unroll
            for (int c = 0; c < 8; ++c) {
                float tv = a8[c] + xr8[c];
                tv = fmaf(LEAKY, fminf(tv, 0.f), fmaxf(tv, 0.f));
                pA = fmaf(tv, att8[c], pA);
                float tw = b8[c] + xr8[c];
                tw = fmaf(LEAKY, fminf(tw, 0.f), fmaxf(tw, 0.f));
                pB = fmaf(tw, att8[c], pB);
            }
            #pragma unroll
            for (int off = 1; off < 16; off <<= 1) {
                pA += __shfl_xor(pA, off);
                pB += __shfl_xor(pB, off);
            }
            float exA = (j + el < end)     ? __expf(pA) : 0.f;
            float exB = (j + 2 + el < end) ? __expf(pB) : 0.f;
            denom += exA + exB;
            #pragma unroll
            for (int c = 0; c < 8; ++c) {
                acc8[c] = fmaf(exA, a8[c], acc8[c]);
                acc8[c] = fmaf(exB, b8[c], acc8[c]);
            }
        }

        // combine edge-halves
        #pragma unroll
        for (int c = 0; c < 8; ++c) acc8[c] += __shfl_xor(acc8[c], 32);
        denom += __shfl_xor(denom, 32);
        float rd = 1.0f / denom;

        float o8[8], bi8[8];
        *(float4*)&bi8[0] = *(const float4*)&bias[c0];
        *(float4*)&bi8[4] = *(const float4*)&bias[c0 + 4];
        #pragma unroll
        for (int c = 0; c < 8; ++c)
            o8[c] = fmaxf(fmaf(acc8[c], rd, bi8[c]), 0.f);

        if (!LAST) {
            if (el == 0) {
                ushort h8[8], lo8[8];
                #pragma unroll
                for (int c = 0; c < 8; ++c) {
                    h8[c]  = f2bf(o8[c]);
                    lo8[c] = f2bf(o8[c] - bf2f(h8[c]));
                }
                *(uint4*)&hhi[(size_t)node * NCH + c0] = *(uint4*)&h8[0];
                *(uint4*)&hlo[(size_t)node * NCH + c0] = *(uint4*)&lo8[0];
            }
        } else {
            float p0 = 0.f, p1 = 0.f, p2 = 0.f, p3 = 0.f;
            #pragma unroll
            for (int c = 0; c < 8; ++c) {
                float4 w4 = *(const float4*)&Wout[(size_t)(c0 + c) * 4];
                p0 = fmaf(o8[c], w4.x, p0);
                p1 = fmaf(o8[c], w4.y, p1);
                p2 = fmaf(o8[c], w4.z, p2);
                p3 = fmaf(o8[c], w4.w, p3);
            }
            #pragma unroll
            for (int off = 1; off < 32; off <<= 1) {
                p0 += __shfl_xor(p0, off);
                p1 += __shfl_xor(p1, off);
                p2 += __shfl_xor(p2, off);
                p3 += __shfl_xor(p3, off);
            }
            if (lane == 0) {
                float4 r;
                r.x = p0 + bout[0]; r.y = p1 + bout[1];
                r.z = p2 + bout[2]; r.w = p3 + bout[3];
                *(float4*)&out[(size_t)node * 4] = r;
            }
        }
    }
}

// ---------------------------------------------------------------------------
extern "C" void kernel_launch(void* const* d_in, const int* in_sizes, int n_in,
                              void* d_out, int out_size, void* d_ws, size_t ws_size,
                              hipStream_t stream) {
    const float* x  = (const float*)d_in[0];
    const int*   ei = (const int*)d_in[1];
    const float* Wl[3]  = {(const float*)d_in[2], (const float*)d_in[6],  (const float*)d_in[10]};
    const float* Wr[3]  = {(const float*)d_in[3], (const float*)d_in[7],  (const float*)d_in[11]};
    const float* att[3] = {(const float*)d_in[4], (const float*)d_in[8],  (const float*)d_in[12]};
    const float* bb[3]  = {(const float*)d_in[5], (const float*)d_in[9],  (const float*)d_in[13]};
    const float* Wout = (const float*)d_in[14];
    const float* bout = (const float*)d_in[15];

    int Nn   = in_sizes[0] / NCH;       // 20000
    int E    = in_sizes[1] / 2;         // 320000
    int Etot = E + Nn;

    size_t NEf = (size_t)Nn * NCH;
    __half* xlh  = (__half*)d_ws;                  // NEf halves
    float*  xr   = (float*)(xlh + NEf);
    ushort* pAhi = (ushort*)(xr + NEf);
    ushort* pAlo = pAhi + NEf;
    ushort* pBhi = pAlo + NEf;
    ushort* pBlo = pBhi + NEf;
    ushort* wthi = pBlo + NEf;                     // 6 * 65536
    ushort* wtlo = wthi + 6 * 65536;
    int*   counts  = (int*)(wtlo + 6 * 65536);
    int*   offsets = counts + Nn;
    int*   cursor  = offsets + (Nn + 1);
    int*   csr_src = cursor + Nn;

    hipMemsetAsync(counts, 0, (size_t)Nn * sizeof(int), stream);
    int eblocks = (Etot + 255) / 256;
    count_kernel<<<eblocks, 256, 0, stream>>>(ei, E, Nn, counts);
    scan_kernel<<<1, 1024, 0, stream>>>(counts, offsets, cursor, Nn);
    scatter_kernel<<<eblocks, 256, 0, stream>>>(ei, E, Nn, cursor, csr_src);

    WPtrs wp = {{Wl[0], Wr[0], Wl[1], Wr[1], Wl[2], Wr[2]}};
    wsplit_kernel<<<dim3(8, 8, 6), dim3(32, 32), 0, stream>>>(wp, wthi, wtlo);

    int n4 = (int)(NEf / 4);
    split_kernel<<<(n4 + 255) / 256, 256, 0, stream>>>(x, pAhi, pAlo, n4);

    dim3 ggrid((Nn + 127) / 128, 4);
    int  nblocks = 2048;
    if (nblocks > (Nn + 3) / 4) nblocks = (Nn + 3) / 4;

    ushort* curHi = pAhi; ushort* curLo = pAlo;
    ushort* nxtHi = pBhi; ushort* nxtLo = pBlo;
    for (int l = 0; l < 3; ++l) {
        dual_gemm_mfma<<<ggrid, 256, 0, stream>>>(
            curHi, curLo, wthi + (size_t)l * 2 * 65536, wtlo + (size_t)l * 2 * 65536,
            xlh, xr, Nn);
        if (l < 2) {
            gat_agg4<0><<<nblocks, 256, 0, stream>>>(xlh, xr, att[l], bb[l],
                offsets, csr_src, nxtHi, nxtLo, nullptr, nullptr, nullptr, Nn);
        } else {
            gat_agg4<1><<<nblocks, 256, 0, stream>>>(xlh, xr, att[l], bb[l],
                offsets, csr_src, nullptr, nullptr, Wout, bout, (float*)d_out, Nn);
        }
        ushort* th = curHi; ushort* tl = curLo;
        curHi = nxtHi; curLo = nxtLo; nxtHi = th; nxtLo = tl;
    }
}

// Round 7
// 259.575 us; speedup vs baseline: 2.3404x; 1.0760x over previous
//
#include <hip/hip_runtime.h>
#include <hip/hip_bf16.h>
#include <hip/hip_fp16.h>
#include <math.h>

// N=20000, E=320000, layers: [N,256]@[256,256] GEMMs, HEADS=2, HID=128.
#define NCH 256
#define LEAKY 0.2f

typedef __attribute__((ext_vector_type(8))) short bf16x8;  // 4 VGPRs
typedef __attribute__((ext_vector_type(4))) float f32x4;   // MFMA C/D
typedef _Float16 half2_t __attribute__((ext_vector_type(2)));

static __device__ __forceinline__ ushort f2bf(float f) {
    unsigned u = __float_as_uint(f);
    u += 0x7fffu + ((u >> 16) & 1u);          // RNE
    return (ushort)(u >> 16);
}
static __device__ __forceinline__ float bf2f(ushort h) {
    return __uint_as_float(((unsigned)h) << 16);
}
static __device__ __forceinline__ half2_t u2h2(unsigned u) {
    return __builtin_bit_cast(half2_t, u);
}

// ---------------------------------------------------------------------------
// CSR build: zero -> counts -> scan -> scatter
// ---------------------------------------------------------------------------
__global__ void zero_kernel(int* __restrict__ p, int n) {
    int i = blockIdx.x * 256 + threadIdx.x;
    if (i < n) p[i] = 0;
}

__global__ void count_kernel(const int* __restrict__ ei, int E, int n,
                             int* __restrict__ counts) {
    int tid = blockIdx.x * 256 + threadIdx.x;
    int tot = E + n;
    if (tid >= tot) return;
    int dst = (tid < E) ? ei[E + tid] : (tid - E);
    atomicAdd(&counts[dst], 1);
}

__global__ void scan_kernel(const int* __restrict__ counts,
                            int* __restrict__ offsets,
                            int* __restrict__ cursor, int n) {
    __shared__ int wsum[16];
    int tid  = threadIdx.x;          // 1024 threads = 16 waves
    int lane = tid & 63, w = tid >> 6;
    int carry = 0;
    for (int base = 0; base < n; base += 1024) {
        int idx = base + tid;
        int v = (idx < n) ? counts[idx] : 0;
        int incl = v;
        #pragma unroll
        for (int off = 1; off < 64; off <<= 1) {
            int t2 = __shfl_up(incl, off, 64);
            if (lane >= off) incl += t2;
        }
        if (lane == 63) wsum[w] = incl;
        __syncthreads();
        if (w == 0 && lane < 16) {
            int s = wsum[lane];
            #pragma unroll
            for (int off = 1; off < 16; off <<= 1) {
                int t2 = __shfl_up(s, off, 64);
                if (lane >= off) s += t2;
            }
            wsum[lane] = s;
        }
        __syncthreads();
        int wpre = (w == 0) ? 0 : wsum[w - 1];
        int excl = carry + wpre + incl - v;
        if (idx < n) { offsets[idx] = excl; cursor[idx] = excl; }
        carry += wsum[15];
        __syncthreads();
    }
    if (tid == 0) offsets[n] = carry;
}

__global__ void scatter_kernel(const int* __restrict__ ei, int E, int n,
                               int* __restrict__ cursor,
                               int* __restrict__ csr_src) {
    int tid = blockIdx.x * 256 + threadIdx.x;
    int tot = E + n;
    if (tid >= tot) return;
    int src, dst;
    if (tid < E) { src = ei[tid]; dst = ei[E + tid]; }
    else         { src = dst = tid - E; }
    int pos = atomicAdd(&cursor[dst], 1);
    csr_src[pos] = src;
}

// ---------------------------------------------------------------------------
// fp32 -> bf16 hi/lo split (layer-1 input x only)
// ---------------------------------------------------------------------------
__global__ void split_kernel(const float* __restrict__ in,
                             ushort* __restrict__ hi, ushort* __restrict__ lo,
                             int n4) {
    int i = blockIdx.x * 256 + threadIdx.x;
    if (i >= n4) return;
    float4 v = ((const float4*)in)[i];
    ushort h0 = f2bf(v.x), h1 = f2bf(v.y), h2 = f2bf(v.z), h3 = f2bf(v.w);
    ((ushort4*)hi)[i] = make_ushort4(h0, h1, h2, h3);
    ((ushort4*)lo)[i] = make_ushort4(f2bf(v.x - bf2f(h0)), f2bf(v.y - bf2f(h1)),
                                     f2bf(v.z - bf2f(h2)), f2bf(v.w - bf2f(h3)));
}

// ---------------------------------------------------------------------------
// Weight transpose+split: W[256,256] -> Wt[256,256] (n-major) bf16 hi/lo.
// ---------------------------------------------------------------------------
struct WPtrs { const float* w[6]; };
__global__ __launch_bounds__(1024) void wsplit_kernel(WPtrs p,
        ushort* __restrict__ hi, ushort* __restrict__ lo) {
    __shared__ float tile[32][33];
    int m = blockIdx.z;
    const float* W = p.w[m];
    size_t base = (size_t)m * 65536;
    int k = blockIdx.y * 32 + threadIdx.y;
    int n = blockIdx.x * 32 + threadIdx.x;
    tile[threadIdx.y][threadIdx.x] = W[k * NCH + n];
    __syncthreads();
    int on = blockIdx.x * 32 + threadIdx.y;
    int ok = blockIdx.y * 32 + threadIdx.x;
    float v = tile[threadIdx.x][threadIdx.y];
    ushort h = f2bf(v);
    hi[base + (size_t)on * NCH + ok] = h;
    lo[base + (size_t)on * NCH + ok] = f2bf(v - bf2f(h));
}

// ---------------------------------------------------------------------------
// MFMA dual GEMM with bf16 hi/lo split (3-product fp32-accurate).
// Flat grid with L2-reuse swizzle: stripes of 32 blocks = 8 row-tiles x 4
// col-blocks; the 4 cb's of one row-tile are 8 dispatches apart -> same XCD
// (round-robin), so the A row-tile is fetched from HBM once and L2-hit 3x.
// ---------------------------------------------------------------------------
#define LDK 40
__global__ __launch_bounds__(256) void dual_gemm_mfma(
        const ushort* __restrict__ Ahi, const ushort* __restrict__ Alo,
        const ushort* __restrict__ Bthi, const ushort* __restrict__ Btlo,
        __half* __restrict__ xlh, float* __restrict__ xr, int M) {
    __shared__ ushort As[2][128 * LDK];
    __shared__ ushort Bs[2][128 * LDK];
    int b = blockIdx.x;
    int stripe = b >> 5;
    int wslot  = b & 31;
    int rt = (stripe << 3) + (wslot & 7);
    int cb = wslot >> 3;
    int row0 = rt * 128;
    if (row0 >= M) return;
    const ushort* Bh = Bthi + (size_t)(cb >> 1) * 65536;
    const ushort* Bl = Btlo + (size_t)(cb >> 1) * 65536;
    int col0 = (cb & 1) * 128;
    int t = threadIdx.x;
    int lane = t & 63, w = t >> 6;
    int wr = w >> 1, wc = w & 1;
    int l15 = lane & 15, l4 = lane >> 4;

    f32x4 acc[4][4];
    #pragma unroll
    for (int i = 0; i < 4; ++i)
        #pragma unroll
        for (int j = 0; j < 4; ++j) acc[i][j] = (f32x4){0.f, 0.f, 0.f, 0.f};

    int r0 = t >> 2,          q0 = (t & 3) * 8;
    int r1 = (t + 256) >> 2,  q1 = ((t + 256) & 3) * 8;

    for (int k0 = 0; k0 < 256; k0 += 32) {
        uint4 z = make_uint4(0, 0, 0, 0);
        uint4 a0h = z, a0l = z, a1h = z, a1l = z;
        if (row0 + r0 < M) {
            a0h = *(const uint4*)&Ahi[(size_t)(row0 + r0) * NCH + k0 + q0];
            a0l = *(const uint4*)&Alo[(size_t)(row0 + r0) * NCH + k0 + q0];
        }
        if (row0 + r1 < M) {
            a1h = *(const uint4*)&Ahi[(size_t)(row0 + r1) * NCH + k0 + q1];
            a1l = *(const uint4*)&Alo[(size_t)(row0 + r1) * NCH + k0 + q1];
        }
        uint4 b0h = *(const uint4*)&Bh[(size_t)(col0 + r0) * NCH + k0 + q0];
        uint4 b0l = *(const uint4*)&Bl[(size_t)(col0 + r0) * NCH + k0 + q0];
        uint4 b1h = *(const uint4*)&Bh[(size_t)(col0 + r1) * NCH + k0 + q1];
        uint4 b1l = *(const uint4*)&Bl[(size_t)(col0 + r1) * NCH + k0 + q1];
        __syncthreads();
        *(uint4*)&As[0][r0 * LDK + q0] = a0h;
        *(uint4*)&As[1][r0 * LDK + q0] = a0l;
        *(uint4*)&As[0][r1 * LDK + q1] = a1h;
        *(uint4*)&As[1][r1 * LDK + q1] = a1l;
        *(uint4*)&Bs[0][r0 * LDK + q0] = b0h;
        *(uint4*)&Bs[1][r0 * LDK + q0] = b0l;
        *(uint4*)&Bs[0][r1 * LDK + q1] = b1h;
        *(uint4*)&Bs[1][r1 * LDK + q1] = b1l;
        __syncthreads();

        bf16x8 af[4][2], bq[4][2];
        #pragma unroll
        for (int fm = 0; fm < 4; ++fm) {
            int addr = (wr * 64 + fm * 16 + l15) * LDK + l4 * 8;
            af[fm][0] = *(const bf16x8*)&As[0][addr];
            af[fm][1] = *(const bf16x8*)&As[1][addr];
        }
        #pragma unroll
        for (int fn = 0; fn < 4; ++fn) {
            int addr = (wc * 64 + fn * 16 + l15) * LDK + l4 * 8;
            bq[fn][0] = *(const bf16x8*)&Bs[0][addr];
            bq[fn][1] = *(const bf16x8*)&Bs[1][addr];
        }
        #pragma unroll
        for (int fm = 0; fm < 4; ++fm)
            #pragma unroll
            for (int fn = 0; fn < 4; ++fn) {
                acc[fm][fn] = __builtin_amdgcn_mfma_f32_16x16x32_bf16(
                    af[fm][0], bq[fn][0], acc[fm][fn], 0, 0, 0);
                acc[fm][fn] = __builtin_amdgcn_mfma_f32_16x16x32_bf16(
                    af[fm][0], bq[fn][1], acc[fm][fn], 0, 0, 0);
                acc[fm][fn] = __builtin_amdgcn_mfma_f32_16x16x32_bf16(
                    af[fm][1], bq[fn][0], acc[fm][fn], 0, 0, 0);
            }
    }

    #pragma unroll
    for (int fm = 0; fm < 4; ++fm)
        #pragma unroll
        for (int fn = 0; fn < 4; ++fn) {
            int col = col0 + wc * 64 + fn * 16 + l15;
            #pragma unroll
            for (int r = 0; r < 4; ++r) {
                int row = row0 + wr * 64 + fm * 16 + l4 * 4 + r;
                if (row < M) {
                    if (cb < 2)
                        xlh[(size_t)row * NCH + col] = __float2half_rn(acc[fm][fn][r]);
                    else
                        xr[(size_t)row * NCH + col] = acc[fm][fn][r];
                }
            }
        }
}

// ---------------------------------------------------------------------------
// GAT aggregation v5: persistent waves, half-wave pair layout, packed-fp16
// dot path (v_pk_add/max/min/fma + v_dot2_f32_f16 exact-f32 accumulate).
// lane = 32*el + l; channels [8l,8l+8); l 0..15 = head0, 16..31 = head1.
// ---------------------------------------------------------------------------
static __device__ __forceinline__ float edge_dot(
        const uint4& r, const half2_t* xrh, const half2_t* atth, float p0) {
    const half2_t zh = (half2_t){(_Float16)0.f, (_Float16)0.f};
    const half2_t ch = (half2_t){(_Float16)LEAKY, (_Float16)LEAKY};
    float p = p0;
    #pragma unroll
    for (int q = 0; q < 4; ++q) {
        unsigned u = (&r.x)[q];
        half2_t t = u2h2(u) + xrh[q];
        half2_t m = __builtin_elementwise_max(t, zh) +
                    ch * __builtin_elementwise_min(t, zh);
        p = __builtin_amdgcn_fdot2(m, atth[q], p, false);
    }
    return p;
}

template <int LAST>
__global__ __launch_bounds__(256) void gat_agg5(
        const __half* __restrict__ xlh, const float* __restrict__ xr,
        const float* __restrict__ att, const float* __restrict__ bias,
        const int* __restrict__ offsets, const int* __restrict__ csr_src,
        ushort* __restrict__ hhi, ushort* __restrict__ hlo,
        const float* __restrict__ Wout, const float* __restrict__ bout,
        float* __restrict__ out, int nNodes) {
    int wid  = threadIdx.x >> 6;
    int lane = threadIdx.x & 63;
    int el = lane >> 5;
    int l  = lane & 31;
    int c0 = l * 8;

    float att8[8];
    *(float4*)&att8[0] = *(const float4*)&att[c0];
    *(float4*)&att8[4] = *(const float4*)&att[c0 + 4];
    half2_t atth[4];
    #pragma unroll
    for (int q = 0; q < 4; ++q)
        atth[q] = (half2_t){(_Float16)att8[2 * q], (_Float16)att8[2 * q + 1]};

    int stride = gridDim.x << 2;
    for (int node0 = (blockIdx.x << 2) + wid; node0 < nNodes; node0 += stride) {
        int node = __builtin_amdgcn_readfirstlane(node0);
        float xr8[8];
        *(float4*)&xr8[0] = *(const float4*)&xr[(size_t)node * NCH + c0];
        *(float4*)&xr8[4] = *(const float4*)&xr[(size_t)node * NCH + c0 + 4];
        half2_t xrh[4];
        #pragma unroll
        for (int q = 0; q < 4; ++q)
            xrh[q] = (half2_t){(_Float16)xr8[2 * q], (_Float16)xr8[2 * q + 1]};

        int begin = offsets[node], end = offsets[node + 1];
        float denom = 0.f;
        float acc8[8];
        #pragma unroll
        for (int c = 0; c < 8; ++c) acc8[c] = 0.f;

        for (int j = begin; j < end; j += 4) {
            int j1 = j + 1 < end ? j + 1 : end - 1;
            int j2 = j + 2 < end ? j + 2 : end - 1;
            int j3 = j + 3 < end ? j + 3 : end - 1;
            int i0 = csr_src[j];
            int i1 = csr_src[j1];
            int i2 = csr_src[j2];
            int i3 = csr_src[j3];
            int sA = el ? i1 : i0;
            int sB = el ? i3 : i2;
            uint4 rA = *(const uint4*)&xlh[(size_t)sA * NCH + c0];
            uint4 rB = *(const uint4*)&xlh[(size_t)sB * NCH + c0];

            float pA = edge_dot(rA, xrh, atth, 0.f);
            float pB = edge_dot(rB, xrh, atth, 0.f);
            #pragma unroll
            for (int off = 1; off < 16; off <<= 1) {
                pA += __shfl_xor(pA, off);
                pB += __shfl_xor(pB, off);
            }
            float exA = (j + el < end)     ? __expf(pA) : 0.f;
            float exB = (j + 2 + el < end) ? __expf(pB) : 0.f;
            denom += exA + exB;
            #pragma unroll
            for (int q = 0; q < 4; ++q) {
                float2 fa = __half22float2(*(const __half2*)&(&rA.x)[q]);
                float2 fb = __half22float2(*(const __half2*)&(&rB.x)[q]);
                acc8[2 * q]     = fmaf(exA, fa.x, acc8[2 * q]);
                acc8[2 * q + 1] = fmaf(exA, fa.y, acc8[2 * q + 1]);
                acc8[2 * q]     = fmaf(exB, fb.x, acc8[2 * q]);
                acc8[2 * q + 1] = fmaf(exB, fb.y, acc8[2 * q + 1]);
            }
        }

        // combine edge-halves
        #pragma unroll
        for (int c = 0; c < 8; ++c) acc8[c] += __shfl_xor(acc8[c], 32);
        denom += __shfl_xor(denom, 32);
        float rd = 1.0f / denom;

        float o8[8], bi8[8];
        *(float4*)&bi8[0] = *(const float4*)&bias[c0];
        *(float4*)&bi8[4] = *(const float4*)&bias[c0 + 4];
        #pragma unroll
        for (int c = 0; c < 8; ++c)
            o8[c] = fmaxf(fmaf(acc8[c], rd, bi8[c]), 0.f);

        if (!LAST) {
            if (el == 0) {
                ushort h8[8], lo8[8];
                #pragma unroll
                for (int c = 0; c < 8; ++c) {
                    h8[c]  = f2bf(o8[c]);
                    lo8[c] = f2bf(o8[c] - bf2f(h8[c]));
                }
                *(uint4*)&hhi[(size_t)node * NCH + c0] = *(uint4*)&h8[0];
                *(uint4*)&hlo[(size_t)node * NCH + c0] = *(uint4*)&lo8[0];
            }
        } else {
            float p0 = 0.f, p1 = 0.f, p2 = 0.f, p3 = 0.f;
            #pragma unroll
            for (int c = 0; c < 8; ++c) {
                float4 w4 = *(const float4*)&Wout[(size_t)(c0 + c) * 4];
                p0 = fmaf(o8[c], w4.x, p0);
                p1 = fmaf(o8[c], w4.y, p1);
                p2 = fmaf(o8[c], w4.z, p2);
                p3 = fmaf(o8[c], w4.w, p3);
            }
            #pragma unroll
            for (int off = 1; off < 32; off <<= 1) {
                p0 += __shfl_xor(p0, off);
                p1 += __shfl_xor(p1, off);
                p2 += __shfl_xor(p2, off);
                p3 += __shfl_xor(p3, off);
            }
            if (lane == 0) {
                float4 r;
                r.x = p0 + bout[0]; r.y = p1 + bout[1];
                r.z = p2 + bout[2]; r.w = p3 + bout[3];
                *(float4*)&out[(size_t)node * 4] = r;
            }
        }
    }
}

// ---------------------------------------------------------------------------
extern "C" void kernel_launch(void* const* d_in, const int* in_sizes, int n_in,
                              void* d_out, int out_size, void* d_ws, size_t ws_size,
                              hipStream_t stream) {
    const float* x  = (const float*)d_in[0];
    const int*   ei = (const int*)d_in[1];
    const float* Wl[3]  = {(const float*)d_in[2], (const float*)d_in[6],  (const float*)d_in[10]};
    const float* Wr[3]  = {(const float*)d_in[3], (const float*)d_in[7],  (const float*)d_in[11]};
    const float* att[3] = {(const float*)d_in[4], (const float*)d_in[8],  (const float*)d_in[12]};
    const float* bb[3]  = {(const float*)d_in[5], (const float*)d_in[9],  (const float*)d_in[13]};
    const float* Wout = (const float*)d_in[14];
    const float* bout = (const float*)d_in[15];

    int Nn   = in_sizes[0] / NCH;       // 20000
    int E    = in_sizes[1] / 2;         // 320000
    int Etot = E + Nn;

    size_t NEf = (size_t)Nn * NCH;
    __half* xlh  = (__half*)d_ws;                  // NEf halves
    float*  xr   = (float*)(xlh + NEf);
    ushort* pAhi = (ushort*)(xr + NEf);
    ushort* pAlo = pAhi + NEf;
    ushort* pBhi = pAlo + NEf;
    ushort* pBlo = pBhi + NEf;
    ushort* wthi = pBlo + NEf;                     // 6 * 65536
    ushort* wtlo = wthi + 6 * 65536;
    int*   counts  = (int*)(wtlo + 6 * 65536);
    int*   offsets = counts + Nn;
    int*   cursor  = offsets + (Nn + 1);
    int*   csr_src = cursor + Nn;

    zero_kernel<<<(Nn + 255) / 256, 256, 0, stream>>>(counts, Nn);
    int eblocks = (Etot + 255) / 256;
    count_kernel<<<eblocks, 256, 0, stream>>>(ei, E, Nn, counts);
    scan_kernel<<<1, 1024, 0, stream>>>(counts, offsets, cursor, Nn);
    scatter_kernel<<<eblocks, 256, 0, stream>>>(ei, E, Nn, cursor, csr_src);

    WPtrs wp = {{Wl[0], Wr[0], Wl[1], Wr[1], Wl[2], Wr[2]}};
    wsplit_kernel<<<dim3(8, 8, 6), dim3(32, 32), 0, stream>>>(wp, wthi, wtlo);

    int n4 = (int)(NEf / 4);
    split_kernel<<<(n4 + 255) / 256, 256, 0, stream>>>(x, pAhi, pAlo, n4);

    int nrt = (Nn + 127) / 128;                    // 157 row tiles
    int prt = ((nrt + 7) / 8) * 8;                 // padded to 8
    int gblocks = prt * 4;                         // 640
    int  nblocks = 2048;
    if (nblocks > (Nn + 3) / 4) nblocks = (Nn + 3) / 4;

    ushort* curHi = pAhi; ushort* curLo = pAlo;
    ushort* nxtHi = pBhi; ushort* nxtLo = pBlo;
    for (int l = 0; l < 3; ++l) {
        dual_gemm_mfma<<<gblocks, 256, 0, stream>>>(
            curHi, curLo, wthi + (size_t)l * 2 * 65536, wtlo + (size_t)l * 2 * 65536,
            xlh, xr, Nn);
        if (l < 2) {
            gat_agg5<0><<<nblocks, 256, 0, stream>>>(xlh, xr, att[l], bb[l],
                offsets, csr_src, nxtHi, nxtLo, nullptr, nullptr, nullptr, Nn);
        } else {
            gat_agg5<1><<<nblocks, 256, 0, stream>>>(xlh, xr, att[l], bb[l],
                offsets, csr_src, nullptr, nullptr, Wout, bout, (float*)d_out, Nn);
        }
        ushort* th = curHi; ushort* tl = curLo;
        curHi = nxtHi; curLo = nxtLo; nxtHi = th; nxtLo = tl;
    }
}